// Round 4
// baseline (486.917 us; speedup 1.0000x reference)
//
#include <hip/hip_runtime.h>

// TemporalGNN: 2x TransformerConv(H=2, C=64) + edge encoder + fc head.
// Edge encoder is rank-1 (edge_attr is [E,1]): eh_l = ea[e]*u_l + c_l.
// Edge phase: stable counting-sort by dst, then one wave per dst node does
// online-softmax attention with a single output write.
// Layer-2 node linears ([50000x128]@[128x512]): split-bf16 MFMA GEMM
// (C = Ah*Bh + Al*Bh + Ah*Bl), accumulating natively in AGPRs -- the vector
// version was stuck at 162us due to AGPR round-trips on 64 f32 accumulators.

#define HC 128   // H*C

typedef __attribute__((ext_vector_type(8))) short bf16x8;
typedef __attribute__((ext_vector_type(4))) float f32x4;

__device__ __forceinline__ unsigned bf16_rne(float f) {
    unsigned u = __float_as_uint(f);
    return (u + 0x7fffu + ((u >> 16) & 1u)) >> 16;
}

// ---------- rank-1 edge-encoder precompute ----------
__global__ void k_uc(const float* __restrict__ We_enc, const float* __restrict__ be_enc,
                     const float* __restrict__ We1, const float* __restrict__ We2,
                     float* __restrict__ uc) {
    int c = threadIdx.x;  // 0..127
    float u1 = 0.f, c1 = 0.f, u2 = 0.f, c2 = 0.f;
    for (int j = 0; j < 64; ++j) {
        float we = We_enc[j], be = be_enc[j];
        float w1 = We1[j * HC + c], w2 = We2[j * HC + c];
        u1 += we * w1; c1 += be * w1;
        u2 += we * w2; c2 += be * w2;
    }
    uc[c] = u1; uc[HC + c] = c1; uc[2 * HC + c] = u2; uc[3 * HC + c] = c2;
}

// ---------- pack layer-2 weights to bf16 hi/lo, B^T layout [n=512][k=128] ----------
__global__ __launch_bounds__(256) void k_wpack(
    const float* __restrict__ Wq, const float* __restrict__ Wk,
    const float* __restrict__ Wv, const float* __restrict__ Ws,
    unsigned short* __restrict__ Bph, unsigned short* __restrict__ Bpl) {
    int t = blockIdx.x * 256 + threadIdx.x;   // 0..65535
    int nn = t >> 7;        // 0..511
    int kk = t & 127;
    int mat = nn >> 7, c = nn & 127;
    const float* W = (mat == 0) ? Wq : (mat == 1) ? Wk : (mat == 2) ? Wv : Ws;
    float w = W[kk * 128 + c];
    unsigned hb = bf16_rne(w);
    float hf = __uint_as_float(hb << 16);
    unsigned lb = bf16_rne(w - hf);
    Bph[nn * 128 + kk] = (unsigned short)hb;
    Bpl[nn * 128 + kk] = (unsigned short)lb;
}

// ---------- CSR build (stable counting sort by dst) ----------
__global__ __launch_bounds__(256) void k_hist(const int* __restrict__ ei, int* __restrict__ deg, int E) {
    int t = blockIdx.x * blockDim.x + threadIdx.x;
    if (t < E) atomicAdd(&deg[ei[E + t]], 1);
}

__global__ __launch_bounds__(1024) void k_scan(const int* __restrict__ deg, int* __restrict__ rowptr, int n) {
    __shared__ int part[1024];
    const int tid = threadIdx.x;
    const int per = (n + 1023) / 1024;
    int b = tid * per;
    int e = min(b + per, n);
    int s = 0;
    for (int i = b; i < e; ++i) s += deg[i];
    part[tid] = s;
    __syncthreads();
    for (int off = 1; off < 1024; off <<= 1) {
        int v = (tid >= off) ? part[tid - off] : 0;
        __syncthreads();
        part[tid] += v;
        __syncthreads();
    }
    int run = (tid == 0) ? 0 : part[tid - 1];
    for (int i = b; i < e; ++i) { rowptr[i] = run; run += deg[i]; }
    if (tid == 1023) rowptr[n] = run;
}

__global__ __launch_bounds__(256) void k_scatter(const int* __restrict__ ei, const int* __restrict__ rowptr,
                                                 int* __restrict__ cursor, int* __restrict__ eid, int E) {
    int t = blockIdx.x * blockDim.x + threadIdx.x;
    if (t >= E) return;
    int dst = ei[E + t];
    int pos = rowptr[dst] + atomicAdd(&cursor[dst], 1);
    eid[pos] = t;
}

__global__ __launch_bounds__(256) void k_bsort(const int* __restrict__ rowptr, int* __restrict__ eid, int n) {
    int t = blockIdx.x * blockDim.x + threadIdx.x;
    if (t >= n) return;
    int b = rowptr[t], e = rowptr[t + 1];
    for (int i = b + 1; i < e; ++i) {
        int key = eid[i];
        int j = i - 1;
        while (j >= b && eid[j] > key) { eid[j + 1] = eid[j]; --j; }
        eid[j + 1] = key;
    }
}

__global__ __launch_bounds__(256) void k_gather(const int* __restrict__ eid, const int* __restrict__ ei,
                                                const float* __restrict__ ea,
                                                int* __restrict__ srcs, float* __restrict__ eas, int E) {
    int t = blockIdx.x * blockDim.x + threadIdx.x;
    if (t >= E) return;
    int id = eid[t];
    srcs[t] = ei[id];
    eas[t] = ea[id];
}

// ---------- layer-1 node linears (K=6, vector ALU) ----------
__global__ __launch_bounds__(256) void k_lin6(
    const float* __restrict__ X, int n,
    const float* __restrict__ Wq, const float* __restrict__ bq,
    const float* __restrict__ Wk, const float* __restrict__ bk,
    const float* __restrict__ Wv, const float* __restrict__ bv,
    const float* __restrict__ Ws, const float* __restrict__ bs,
    float* __restrict__ q, float* __restrict__ k,
    float* __restrict__ v, float* __restrict__ o) {
    __shared__ float xs[16][6];
    const int base = blockIdx.x * 16;
    const int tid = threadIdx.x;
    for (int i = tid; i < 16 * 6; i += 256) {
        int ni = base + i / 6;
        xs[i / 6][i % 6] = (ni < n) ? X[(size_t)ni * 6 + (i % 6)] : 0.f;
    }
    __syncthreads();
    const int c = tid & 127;
    const int m = tid >> 7;  // 0 -> (q,k), 1 -> (v,o)
    const float* WA = m ? Wv : Wq;
    const float* WB = m ? Ws : Wk;
    float accA[16], accB[16];
#pragma unroll
    for (int i = 0; i < 16; ++i) { accA[i] = 0.f; accB[i] = 0.f; }
    for (int j = 0; j < 6; ++j) {
        float w0 = WA[j * HC + c];
        float w1 = WB[j * HC + c];
#pragma unroll
        for (int i = 0; i < 16; ++i) {
            float xv = xs[i][j];
            accA[i] += xv * w0;
            accB[i] += xv * w1;
        }
    }
    const float bA = m ? bv[c] : bq[c];
    const float bB = m ? bs[c] : bk[c];
    float* oA = m ? v : q;
    float* oB = m ? o : k;
#pragma unroll
    for (int i = 0; i < 16; ++i) {
        int ni = base + i;
        if (ni < n) {
            oA[(size_t)ni * HC + c] = accA[i] + bA;
            oB[(size_t)ni * HC + c] = accB[i] + bB;
        }
    }
}

// ---------- layer-2 node linears: split-bf16 MFMA GEMM ----------
// [n x 128] @ [128 x 512] -> q,k,v,o. Block = 32 nodes x 512 cols, 4 waves:
// wave (wid>>1) picks node half, (wid&1) picks col half (256 each).
// A from hhi/hlo [node][k] bf16; B from Bph/Bpl [ncol][k] bf16 (B^T layout).
// Both frags use identical contiguous k-octet indexing -> any HW k-permutation
// cancels. C/D: col=lane&15, row=(lane>>4)*4+reg (HW-verified mapping).
__global__ __launch_bounds__(256, 2) void k_lin2(
    const unsigned short* __restrict__ hhi, const unsigned short* __restrict__ hlo,
    const unsigned short* __restrict__ Bph, const unsigned short* __restrict__ Bpl,
    const float* __restrict__ bq, const float* __restrict__ bk,
    const float* __restrict__ bv, const float* __restrict__ bs,
    float* __restrict__ q, float* __restrict__ k,
    float* __restrict__ v, float* __restrict__ o, int n) {
    const int tid = threadIdx.x;
    const int wid = tid >> 6, l = tid & 63;
    const int mrow = (wid >> 1) * 16;     // 0 or 16
    const int nbase = (wid & 1) * 256;    // 0 or 256
    const int mb = blockIdx.x * 32;
    const int la = l & 15, lk = l >> 4;
    int node_a = mb + mrow + la;
    if (node_a >= n) node_a = n - 1;
    f32x4 acc[16];
#pragma unroll
    for (int nt = 0; nt < 16; ++nt) acc[nt] = (f32x4){0.f, 0.f, 0.f, 0.f};
#pragma unroll
    for (int ks = 0; ks < 4; ++ks) {
        const int koff = lk * 8 + ks * 32;
        bf16x8 Ah = *(const bf16x8*)&hhi[(size_t)node_a * 128 + koff];
        bf16x8 Al = *(const bf16x8*)&hlo[(size_t)node_a * 128 + koff];
#pragma unroll
        for (int nt = 0; nt < 16; ++nt) {
            const int nn = nbase + nt * 16 + la;
            bf16x8 Bh = *(const bf16x8*)&Bph[(size_t)nn * 128 + koff];
            bf16x8 Bl = *(const bf16x8*)&Bpl[(size_t)nn * 128 + koff];
            acc[nt] = __builtin_amdgcn_mfma_f32_16x16x32_bf16(Ah, Bh, acc[nt], 0, 0, 0);
            acc[nt] = __builtin_amdgcn_mfma_f32_16x16x32_bf16(Al, Bh, acc[nt], 0, 0, 0);
            acc[nt] = __builtin_amdgcn_mfma_f32_16x16x32_bf16(Ah, Bl, acc[nt], 0, 0, 0);
        }
    }
    const int crow0 = mb + mrow + lk * 4;
#pragma unroll
    for (int nt = 0; nt < 16; ++nt) {
        const int cg = nbase + nt * 16;
        const int mat = cg >> 7;
        const int col = (cg & 127) + la;
        const float* bias = (mat == 0) ? bq : (mat == 1) ? bk : (mat == 2) ? bv : bs;
        float* out = (mat == 0) ? q : (mat == 1) ? k : (mat == 2) ? v : o;
        const float bb = bias[col];
#pragma unroll
        for (int j = 0; j < 4; ++j) {
            int node = crow0 + j;
            if (node < n) out[(size_t)node * 128 + col] = acc[nt][j] + bb;
        }
    }
}

// ---------- fused online-softmax attention, one wave per dst node ----------
// Lane l holds channels {2l, 2l+1}; lanes 0..31 = head0, 32..63 = head1.
// MODE 1 (layer 1): out = relu(attn + skip), stored as bf16 hi/lo pair only.
// MODE 0 (layer 2): out = attn + skip, stored f32 into io.
template <int MODE>
__global__ __launch_bounds__(256) void k_attn(
    const float* __restrict__ q, const float* __restrict__ k, const float* __restrict__ v,
    const int* __restrict__ rowptr, const int* __restrict__ srcs, const float* __restrict__ eas,
    const float* __restrict__ ucu, const float* __restrict__ ucc,
    float* __restrict__ io, unsigned short* __restrict__ hhi, unsigned short* __restrict__ hlo,
    int n) {
    int wid = (int)((blockIdx.x * (size_t)blockDim.x + threadIdx.x) >> 6);
    int lane = threadIdx.x & 63;
    if (wid >= n) return;
    const float2* q2 = (const float2*)q;
    const float2* k2 = (const float2*)k;
    const float2* v2 = (const float2*)v;
    float2 qr = q2[(size_t)wid * 64 + lane];
    float2 uu = ((const float2*)ucu)[lane];
    float2 cc = ((const float2*)ucc)[lane];
    int b = rowptr[wid], e = rowptr[wid + 1];
    float m = -INFINITY, s = 0.f;
    float ax = 0.f, ay = 0.f;
    for (int p = b; p < e; ++p) {
        int src = srcs[p];
        float eav = eas[p];
        float2 kr = k2[(size_t)src * 64 + lane];
        float2 vr = v2[(size_t)src * 64 + lane];
        float eh0 = eav * uu.x + cc.x;
        float eh1 = eav * uu.y + cc.y;
        float d = qr.x * (kr.x + eh0) + qr.y * (kr.y + eh1);
        d += __shfl_xor(d, 1); d += __shfl_xor(d, 2); d += __shfl_xor(d, 4);
        d += __shfl_xor(d, 8); d += __shfl_xor(d, 16);   // per-head (32-lane) sum
        float a = d * 0.125f;                            // / sqrt(64)
        float nm = fmaxf(m, a);
        float sc = __expf(m - nm);
        float pw = __expf(a - nm);
        s = s * sc + pw;
        ax = ax * sc + pw * (vr.x + eh0);
        ay = ay * sc + pw * (vr.y + eh1);
        m = nm;
    }
    float inv = 1.f / (s + 1e-16f);
    float2 skip = ((const float2*)io)[(size_t)wid * 64 + lane];
    float o0 = ax * inv + skip.x;
    float o1 = ay * inv + skip.y;
    if (MODE == 1) {
        o0 = fmaxf(o0, 0.f); o1 = fmaxf(o1, 0.f);
        unsigned h0 = bf16_rne(o0);
        unsigned h1 = bf16_rne(o1);
        float r0 = o0 - __uint_as_float(h0 << 16);
        float r1 = o1 - __uint_as_float(h1 << 16);
        unsigned l0 = bf16_rne(r0);
        unsigned l1 = bf16_rne(r1);
        ushort2* ph = (ushort2*)&hhi[(size_t)wid * 128 + 2 * lane];
        ushort2* pl = (ushort2*)&hlo[(size_t)wid * 128 + 2 * lane];
        *ph = make_ushort2((unsigned short)h0, (unsigned short)h1);
        *pl = make_ushort2((unsigned short)l0, (unsigned short)l1);
    } else {
        ((float2*)io)[(size_t)wid * 64 + lane] = make_float2(o0, o1);
    }
}

// ---------- fc head (relu fused), one wave per node ----------
__global__ __launch_bounds__(256) void k_fc(
    const float* __restrict__ h, const float* __restrict__ Wfc,
    const float* __restrict__ bfc, float* __restrict__ out, int n) {
    int w = (int)((blockIdx.x * (size_t)blockDim.x + threadIdx.x) >> 6);
    int lane = threadIdx.x & 63;
    if (w >= n) return;
    const float2* h2 = (const float2*)h;
    const float2* w2 = (const float2*)Wfc;
    float2 hv = h2[(size_t)w * 64 + lane];
    float2 wv = w2[lane];
    float vsum = fmaxf(hv.x, 0.f) * wv.x + fmaxf(hv.y, 0.f) * wv.y;
#pragma unroll
    for (int off = 1; off < 64; off <<= 1) vsum += __shfl_xor(vsum, off);
    if (lane == 0) out[w] = vsum + bfc[0];
}

extern "C" void kernel_launch(void* const* d_in, const int* in_sizes, int n_in,
                              void* d_out, int out_size, void* d_ws, size_t ws_size,
                              hipStream_t stream) {
    const float* x      = (const float*)d_in[0];
    const int*   ei     = (const int*)d_in[1];
    const float* ea     = (const float*)d_in[2];
    const float* We_enc = (const float*)d_in[3];
    const float* be_enc = (const float*)d_in[4];
    const float* Wq1 = (const float*)d_in[5],  *bq1 = (const float*)d_in[6];
    const float* Wk1 = (const float*)d_in[7],  *bk1 = (const float*)d_in[8];
    const float* Wv1 = (const float*)d_in[9],  *bv1 = (const float*)d_in[10];
    const float* We1 = (const float*)d_in[11];
    const float* Ws1 = (const float*)d_in[12], *bs1 = (const float*)d_in[13];
    const float* Wq2 = (const float*)d_in[14], *bq2 = (const float*)d_in[15];
    const float* Wk2 = (const float*)d_in[16], *bk2 = (const float*)d_in[17];
    const float* Wv2 = (const float*)d_in[18], *bv2 = (const float*)d_in[19];
    const float* We2 = (const float*)d_in[20];
    const float* Ws2 = (const float*)d_in[21], *bs2 = (const float*)d_in[22];
    const float* Wfc = (const float*)d_in[23], *bfc = (const float*)d_in[24];

    const int n = in_sizes[0] / 6;   // 50000
    const int E = in_sizes[2];       // 409600

    float* ws = (float*)d_ws;
    size_t off = 0;
    float* qb = ws + off; off += (size_t)n * HC;
    float* kb = ws + off; off += (size_t)n * HC;
    float* vb = ws + off; off += (size_t)n * HC;
    float* Bb = ws + off; off += (size_t)n * HC;   // skip-init / h buffer
    int* rowptr = (int*)(ws + off); off += (size_t)(n + 1);
    int* deg    = (int*)(ws + off); off += (size_t)n;   // also scatter cursor
    int* eid    = (int*)(ws + off); off += (size_t)E;
    int* srcs   = (int*)(ws + off); off += (size_t)E;
    float* eas  = ws + off; off += (size_t)E;
    float* uc   = ws + off; off += 512;
    unsigned short* hhi = (unsigned short*)(ws + off); off += (size_t)n * HC / 2;
    unsigned short* hlo = (unsigned short*)(ws + off); off += (size_t)n * HC / 2;
    unsigned short* Bph = (unsigned short*)(ws + off); off += 512 * 128 / 2;
    unsigned short* Bpl = (unsigned short*)(ws + off); off += 512 * 128 / 2;

    const int eb = (E + 255) / 256;
    const int nb = (n + 255) / 256;
    const int wb = (int)(((size_t)n * 64 + 255) / 256);

    hipLaunchKernelGGL(k_uc, dim3(1), dim3(128), 0, stream, We_enc, be_enc, We1, We2, uc);
    hipLaunchKernelGGL(k_wpack, dim3(256), dim3(256), 0, stream, Wq2, Wk2, Wv2, Ws2, Bph, Bpl);

    // ---- CSR build (shared by both layers) ----
    hipMemsetAsync(deg, 0, (size_t)n * sizeof(int), stream);
    hipLaunchKernelGGL(k_hist, dim3(eb), dim3(256), 0, stream, ei, deg, E);
    hipLaunchKernelGGL(k_scan, dim3(1), dim3(1024), 0, stream, deg, rowptr, n);
    hipMemsetAsync(deg, 0, (size_t)n * sizeof(int), stream);  // reuse as cursor
    hipLaunchKernelGGL(k_scatter, dim3(eb), dim3(256), 0, stream, ei, rowptr, deg, eid, E);
    hipLaunchKernelGGL(k_bsort, dim3(nb), dim3(256), 0, stream, rowptr, eid, n);
    hipLaunchKernelGGL(k_gather, dim3(eb), dim3(256), 0, stream, eid, ei, ea, srcs, eas, E);

    // ---- layer 1 ----
    hipLaunchKernelGGL(k_lin6, dim3((n + 15) / 16), dim3(256), 0, stream,
                       x, n, Wq1, bq1, Wk1, bk1, Wv1, bv1, Ws1, bs1, qb, kb, vb, Bb);
    hipLaunchKernelGGL((k_attn<1>), dim3(wb), dim3(256), 0, stream,
                       qb, kb, vb, rowptr, srcs, eas, uc, uc + HC, Bb, hhi, hlo, n);

    // ---- layer 2 (MFMA GEMM reads hhi/hlo, writes q,k,v + fresh skip into Bb) ----
    hipLaunchKernelGGL(k_lin2, dim3((n + 31) / 32), dim3(256), 0, stream,
                       hhi, hlo, Bph, Bpl, bq2, bk2, bv2, bs2, qb, kb, vb, Bb, n);
    hipLaunchKernelGGL((k_attn<0>), dim3(wb), dim3(256), 0, stream,
                       qb, kb, vb, rowptr, srcs, eas, uc + 2 * HC, uc + 3 * HC, Bb,
                       (unsigned short*)nullptr, (unsigned short*)nullptr, n);

    // ---- fc head ----
    hipLaunchKernelGGL(k_fc, dim3(wb), dim3(256), 0, stream, Bb, Wfc, bfc, (float*)d_out, n);
}

// Round 5
// 429.153 us; speedup vs baseline: 1.1346x; 1.1346x over previous
//
#include <hip/hip_runtime.h>

// TemporalGNN: 2x TransformerConv(H=2, C=64) + edge encoder + fc head.
// Edge encoder is rank-1 (edge_attr is [E,1]): eh_l = ea[e]*u_l + c_l.
// Edge phase: stable counting-sort by dst, then one wave per dst node does
// online-softmax attention with a single output write.
// Layer-2 node linears ([50000x128]@[128x512]): split-bf16 MFMA GEMM
// (C = Ah*Bh + Al*Bh + Ah*Bl) with the B panel staged in LDS (64 KB,
// XOR-swizzled). R4's global-B version was latency-bound at 147us re-reading
// 800 MB of B fragments from L2; LDS staging cuts that to 200 MB and hides it.

#define HC 128   // H*C

typedef __attribute__((ext_vector_type(8))) short bf16x8;
typedef __attribute__((ext_vector_type(4))) float f32x4;

__device__ __forceinline__ unsigned bf16_rne(float f) {
    unsigned u = __float_as_uint(f);
    return (u + 0x7fffu + ((u >> 16) & 1u)) >> 16;
}

// ---------- rank-1 edge-encoder precompute ----------
__global__ void k_uc(const float* __restrict__ We_enc, const float* __restrict__ be_enc,
                     const float* __restrict__ We1, const float* __restrict__ We2,
                     float* __restrict__ uc) {
    int c = threadIdx.x;  // 0..127
    float u1 = 0.f, c1 = 0.f, u2 = 0.f, c2 = 0.f;
    for (int j = 0; j < 64; ++j) {
        float we = We_enc[j], be = be_enc[j];
        float w1 = We1[j * HC + c], w2 = We2[j * HC + c];
        u1 += we * w1; c1 += be * w1;
        u2 += we * w2; c2 += be * w2;
    }
    uc[c] = u1; uc[HC + c] = c1; uc[2 * HC + c] = u2; uc[3 * HC + c] = c2;
}

// ---------- pack layer-2 weights to bf16 hi/lo, B^T layout [n=512][k=128] ----------
__global__ __launch_bounds__(256) void k_wpack(
    const float* __restrict__ Wq, const float* __restrict__ Wk,
    const float* __restrict__ Wv, const float* __restrict__ Ws,
    unsigned short* __restrict__ Bph, unsigned short* __restrict__ Bpl) {
    int t = blockIdx.x * 256 + threadIdx.x;   // 0..65535
    int nn = t >> 7;        // 0..511
    int kk = t & 127;
    int mat = nn >> 7, c = nn & 127;
    const float* W = (mat == 0) ? Wq : (mat == 1) ? Wk : (mat == 2) ? Wv : Ws;
    float w = W[kk * 128 + c];
    unsigned hb = bf16_rne(w);
    float hf = __uint_as_float(hb << 16);
    unsigned lb = bf16_rne(w - hf);
    Bph[nn * 128 + kk] = (unsigned short)hb;
    Bpl[nn * 128 + kk] = (unsigned short)lb;
}

// ---------- CSR build (stable counting sort by dst) ----------
__global__ __launch_bounds__(256) void k_hist(const int* __restrict__ ei, int* __restrict__ deg, int E) {
    int t = blockIdx.x * blockDim.x + threadIdx.x;
    if (t < E) atomicAdd(&deg[ei[E + t]], 1);
}

__global__ __launch_bounds__(1024) void k_scan(const int* __restrict__ deg, int* __restrict__ rowptr, int n) {
    __shared__ int part[1024];
    const int tid = threadIdx.x;
    const int per = (n + 1023) / 1024;
    int b = tid * per;
    int e = min(b + per, n);
    int s = 0;
    for (int i = b; i < e; ++i) s += deg[i];
    part[tid] = s;
    __syncthreads();
    for (int off = 1; off < 1024; off <<= 1) {
        int v = (tid >= off) ? part[tid - off] : 0;
        __syncthreads();
        part[tid] += v;
        __syncthreads();
    }
    int run = (tid == 0) ? 0 : part[tid - 1];
    for (int i = b; i < e; ++i) { rowptr[i] = run; run += deg[i]; }
    if (tid == 1023) rowptr[n] = run;
}

__global__ __launch_bounds__(256) void k_scatter(const int* __restrict__ ei, const int* __restrict__ rowptr,
                                                 int* __restrict__ cursor, int* __restrict__ eid, int E) {
    int t = blockIdx.x * blockDim.x + threadIdx.x;
    if (t >= E) return;
    int dst = ei[E + t];
    int pos = rowptr[dst] + atomicAdd(&cursor[dst], 1);
    eid[pos] = t;
}

__global__ __launch_bounds__(256) void k_bsort(const int* __restrict__ rowptr, int* __restrict__ eid, int n) {
    int t = blockIdx.x * blockDim.x + threadIdx.x;
    if (t >= n) return;
    int b = rowptr[t], e = rowptr[t + 1];
    for (int i = b + 1; i < e; ++i) {
        int key = eid[i];
        int j = i - 1;
        while (j >= b && eid[j] > key) { eid[j + 1] = eid[j]; --j; }
        eid[j + 1] = key;
    }
}

__global__ __launch_bounds__(256) void k_gather(const int* __restrict__ eid, const int* __restrict__ ei,
                                                const float* __restrict__ ea,
                                                int* __restrict__ srcs, float* __restrict__ eas, int E) {
    int t = blockIdx.x * blockDim.x + threadIdx.x;
    if (t >= E) return;
    int id = eid[t];
    srcs[t] = ei[id];
    eas[t] = ea[id];
}

// ---------- layer-1 node linears (K=6, vector ALU) ----------
__global__ __launch_bounds__(256) void k_lin6(
    const float* __restrict__ X, int n,
    const float* __restrict__ Wq, const float* __restrict__ bq,
    const float* __restrict__ Wk, const float* __restrict__ bk,
    const float* __restrict__ Wv, const float* __restrict__ bv,
    const float* __restrict__ Ws, const float* __restrict__ bs,
    float* __restrict__ q, float* __restrict__ k,
    float* __restrict__ v, float* __restrict__ o) {
    __shared__ float xs[16][6];
    const int base = blockIdx.x * 16;
    const int tid = threadIdx.x;
    for (int i = tid; i < 16 * 6; i += 256) {
        int ni = base + i / 6;
        xs[i / 6][i % 6] = (ni < n) ? X[(size_t)ni * 6 + (i % 6)] : 0.f;
    }
    __syncthreads();
    const int c = tid & 127;
    const int m = tid >> 7;  // 0 -> (q,k), 1 -> (v,o)
    const float* WA = m ? Wv : Wq;
    const float* WB = m ? Ws : Wk;
    float accA[16], accB[16];
#pragma unroll
    for (int i = 0; i < 16; ++i) { accA[i] = 0.f; accB[i] = 0.f; }
    for (int j = 0; j < 6; ++j) {
        float w0 = WA[j * HC + c];
        float w1 = WB[j * HC + c];
#pragma unroll
        for (int i = 0; i < 16; ++i) {
            float xv = xs[i][j];
            accA[i] += xv * w0;
            accB[i] += xv * w1;
        }
    }
    const float bA = m ? bv[c] : bq[c];
    const float bB = m ? bs[c] : bk[c];
    float* oA = m ? v : q;
    float* oB = m ? o : k;
#pragma unroll
    for (int i = 0; i < 16; ++i) {
        int ni = base + i;
        if (ni < n) {
            oA[(size_t)ni * HC + c] = accA[i] + bA;
            oB[(size_t)ni * HC + c] = accB[i] + bB;
        }
    }
}

// ---------- layer-2 node linears: split-bf16 MFMA GEMM, LDS-staged B ----------
// Grid (ceil(n/64), 4). blockIdx.y = col quarter = matrix {q,k,v,s}.
// Block stages that matrix's [128 cols][128 k] hi+lo bf16 panel (64 KB) into
// LDS (XOR swizzle: element offset ^= (row&7)<<3 -> <=2-way bank conflicts),
// then 4 waves x 16 nodes x (8 col-tiles x 4 k-steps x 3 MFMA) out of LDS.
__global__ __launch_bounds__(256, 2) void k_lin2(
    const unsigned short* __restrict__ hhi, const unsigned short* __restrict__ hlo,
    const unsigned short* __restrict__ Bph, const unsigned short* __restrict__ Bpl,
    const float* __restrict__ bq, const float* __restrict__ bk,
    const float* __restrict__ bv, const float* __restrict__ bs,
    float* __restrict__ q, float* __restrict__ k,
    float* __restrict__ v, float* __restrict__ o, int n) {
    __shared__ unsigned short Bs[2][128][128];   // 64 KB
    const int tid = threadIdx.x;
    const int cq = blockIdx.y;                   // matrix index
    // stage: i indexes [h][row][16B-chunk] = [2][128][16]
    for (int i = tid; i < 2 * 128 * 16; i += 256) {
        int kk8 = i & 15;
        int nnl = (i >> 4) & 127;
        int h = i >> 11;
        const unsigned short* src = h ? Bpl : Bph;
        bf16x8 val = *(const bf16x8*)&src[((size_t)(cq * 128 + nnl)) * 128 + kk8 * 8];
        int swk = (kk8 ^ (nnl & 7)) * 8;
        *(bf16x8*)&Bs[h][nnl][swk] = val;
    }
    __syncthreads();

    const int wid = tid >> 6, l = tid & 63;
    const int la = l & 15, lk = l >> 4;
    const int mb = blockIdx.x * 64;
    int node_a = mb + wid * 16 + la;
    if (node_a >= n) node_a = n - 1;
    const int sw = (la & 7) << 3;
    f32x4 acc[8];
#pragma unroll
    for (int nt = 0; nt < 8; ++nt) acc[nt] = (f32x4){0.f, 0.f, 0.f, 0.f};
#pragma unroll
    for (int ks = 0; ks < 4; ++ks) {
        const int koff = lk * 8 + ks * 32;
        bf16x8 Ah = *(const bf16x8*)&hhi[(size_t)node_a * 128 + koff];
        bf16x8 Al = *(const bf16x8*)&hlo[(size_t)node_a * 128 + koff];
        const int rk = koff ^ sw;
#pragma unroll
        for (int nt = 0; nt < 8; ++nt) {
            const int nnl = nt * 16 + la;
            bf16x8 Bh = *(const bf16x8*)&Bs[0][nnl][rk];
            bf16x8 Bl = *(const bf16x8*)&Bs[1][nnl][rk];
            acc[nt] = __builtin_amdgcn_mfma_f32_16x16x32_bf16(Ah, Bh, acc[nt], 0, 0, 0);
            acc[nt] = __builtin_amdgcn_mfma_f32_16x16x32_bf16(Al, Bh, acc[nt], 0, 0, 0);
            acc[nt] = __builtin_amdgcn_mfma_f32_16x16x32_bf16(Ah, Bl, acc[nt], 0, 0, 0);
        }
    }
    const float* bias = (cq == 0) ? bq : (cq == 1) ? bk : (cq == 2) ? bv : bs;
    float* out = (cq == 0) ? q : (cq == 1) ? k : (cq == 2) ? v : o;
    const int crow0 = mb + wid * 16 + lk * 4;
#pragma unroll
    for (int nt = 0; nt < 8; ++nt) {
        const int col = nt * 16 + la;
        const float bb = bias[col];
#pragma unroll
        for (int j = 0; j < 4; ++j) {
            int node = crow0 + j;
            if (node < n) out[(size_t)node * 128 + col] = acc[nt][j] + bb;
        }
    }
}

// ---------- fused online-softmax attention, one wave per dst node ----------
// Lane l holds channels {2l, 2l+1}; lanes 0..31 = head0, 32..63 = head1.
// MODE 1 (layer 1): out = relu(attn + skip), stored as bf16 hi/lo pair only.
// MODE 0 (layer 2): out = attn + skip, stored f32 into io.
template <int MODE>
__global__ __launch_bounds__(256) void k_attn(
    const float* __restrict__ q, const float* __restrict__ k, const float* __restrict__ v,
    const int* __restrict__ rowptr, const int* __restrict__ srcs, const float* __restrict__ eas,
    const float* __restrict__ ucu, const float* __restrict__ ucc,
    float* __restrict__ io, unsigned short* __restrict__ hhi, unsigned short* __restrict__ hlo,
    int n) {
    int wid = (int)((blockIdx.x * (size_t)blockDim.x + threadIdx.x) >> 6);
    int lane = threadIdx.x & 63;
    if (wid >= n) return;
    const float2* q2 = (const float2*)q;
    const float2* k2 = (const float2*)k;
    const float2* v2 = (const float2*)v;
    float2 qr = q2[(size_t)wid * 64 + lane];
    float2 uu = ((const float2*)ucu)[lane];
    float2 cc = ((const float2*)ucc)[lane];
    int b = rowptr[wid], e = rowptr[wid + 1];
    float m = -INFINITY, s = 0.f;
    float ax = 0.f, ay = 0.f;
    for (int p = b; p < e; ++p) {
        int src = srcs[p];
        float eav = eas[p];
        float2 kr = k2[(size_t)src * 64 + lane];
        float2 vr = v2[(size_t)src * 64 + lane];
        float eh0 = eav * uu.x + cc.x;
        float eh1 = eav * uu.y + cc.y;
        float d = qr.x * (kr.x + eh0) + qr.y * (kr.y + eh1);
        d += __shfl_xor(d, 1); d += __shfl_xor(d, 2); d += __shfl_xor(d, 4);
        d += __shfl_xor(d, 8); d += __shfl_xor(d, 16);   // per-head (32-lane) sum
        float a = d * 0.125f;                            // / sqrt(64)
        float nm = fmaxf(m, a);
        float sc = __expf(m - nm);
        float pw = __expf(a - nm);
        s = s * sc + pw;
        ax = ax * sc + pw * (vr.x + eh0);
        ay = ay * sc + pw * (vr.y + eh1);
        m = nm;
    }
    float inv = 1.f / (s + 1e-16f);
    float2 skip = ((const float2*)io)[(size_t)wid * 64 + lane];
    float o0 = ax * inv + skip.x;
    float o1 = ay * inv + skip.y;
    if (MODE == 1) {
        o0 = fmaxf(o0, 0.f); o1 = fmaxf(o1, 0.f);
        unsigned h0 = bf16_rne(o0);
        unsigned h1 = bf16_rne(o1);
        float r0 = o0 - __uint_as_float(h0 << 16);
        float r1 = o1 - __uint_as_float(h1 << 16);
        unsigned l0 = bf16_rne(r0);
        unsigned l1 = bf16_rne(r1);
        ushort2* ph = (ushort2*)&hhi[(size_t)wid * 128 + 2 * lane];
        ushort2* pl = (ushort2*)&hlo[(size_t)wid * 128 + 2 * lane];
        *ph = make_ushort2((unsigned short)h0, (unsigned short)h1);
        *pl = make_ushort2((unsigned short)l0, (unsigned short)l1);
    } else {
        ((float2*)io)[(size_t)wid * 64 + lane] = make_float2(o0, o1);
    }
}

// ---------- fc head (relu fused), one wave per node ----------
__global__ __launch_bounds__(256) void k_fc(
    const float* __restrict__ h, const float* __restrict__ Wfc,
    const float* __restrict__ bfc, float* __restrict__ out, int n) {
    int w = (int)((blockIdx.x * (size_t)blockDim.x + threadIdx.x) >> 6);
    int lane = threadIdx.x & 63;
    if (w >= n) return;
    const float2* h2 = (const float2*)h;
    const float2* w2 = (const float2*)Wfc;
    float2 hv = h2[(size_t)w * 64 + lane];
    float2 wv = w2[lane];
    float vsum = fmaxf(hv.x, 0.f) * wv.x + fmaxf(hv.y, 0.f) * wv.y;
#pragma unroll
    for (int off = 1; off < 64; off <<= 1) vsum += __shfl_xor(vsum, off);
    if (lane == 0) out[w] = vsum + bfc[0];
}

extern "C" void kernel_launch(void* const* d_in, const int* in_sizes, int n_in,
                              void* d_out, int out_size, void* d_ws, size_t ws_size,
                              hipStream_t stream) {
    const float* x      = (const float*)d_in[0];
    const int*   ei     = (const int*)d_in[1];
    const float* ea     = (const float*)d_in[2];
    const float* We_enc = (const float*)d_in[3];
    const float* be_enc = (const float*)d_in[4];
    const float* Wq1 = (const float*)d_in[5],  *bq1 = (const float*)d_in[6];
    const float* Wk1 = (const float*)d_in[7],  *bk1 = (const float*)d_in[8];
    const float* Wv1 = (const float*)d_in[9],  *bv1 = (const float*)d_in[10];
    const float* We1 = (const float*)d_in[11];
    const float* Ws1 = (const float*)d_in[12], *bs1 = (const float*)d_in[13];
    const float* Wq2 = (const float*)d_in[14], *bq2 = (const float*)d_in[15];
    const float* Wk2 = (const float*)d_in[16], *bk2 = (const float*)d_in[17];
    const float* Wv2 = (const float*)d_in[18], *bv2 = (const float*)d_in[19];
    const float* We2 = (const float*)d_in[20];
    const float* Ws2 = (const float*)d_in[21], *bs2 = (const float*)d_in[22];
    const float* Wfc = (const float*)d_in[23], *bfc = (const float*)d_in[24];

    const int n = in_sizes[0] / 6;   // 50000
    const int E = in_sizes[2];       // 409600

    float* ws = (float*)d_ws;
    size_t off = 0;
    float* qb = ws + off; off += (size_t)n * HC;
    float* kb = ws + off; off += (size_t)n * HC;
    float* vb = ws + off; off += (size_t)n * HC;
    float* Bb = ws + off; off += (size_t)n * HC;   // skip-init / h buffer
    int* rowptr = (int*)(ws + off); off += (size_t)(n + 1);
    int* deg    = (int*)(ws + off); off += (size_t)n;   // also scatter cursor
    int* eid    = (int*)(ws + off); off += (size_t)E;
    int* srcs   = (int*)(ws + off); off += (size_t)E;
    float* eas  = ws + off; off += (size_t)E;
    float* uc   = ws + off; off += 512;
    unsigned short* hhi = (unsigned short*)(ws + off); off += (size_t)n * HC / 2;
    unsigned short* hlo = (unsigned short*)(ws + off); off += (size_t)n * HC / 2;
    unsigned short* Bph = (unsigned short*)(ws + off); off += 512 * 128 / 2;
    unsigned short* Bpl = (unsigned short*)(ws + off); off += 512 * 128 / 2;

    const int eb = (E + 255) / 256;
    const int nb = (n + 255) / 256;
    const int wb = (int)(((size_t)n * 64 + 255) / 256);

    hipLaunchKernelGGL(k_uc, dim3(1), dim3(128), 0, stream, We_enc, be_enc, We1, We2, uc);
    hipLaunchKernelGGL(k_wpack, dim3(256), dim3(256), 0, stream, Wq2, Wk2, Wv2, Ws2, Bph, Bpl);

    // ---- CSR build (shared by both layers) ----
    hipMemsetAsync(deg, 0, (size_t)n * sizeof(int), stream);
    hipLaunchKernelGGL(k_hist, dim3(eb), dim3(256), 0, stream, ei, deg, E);
    hipLaunchKernelGGL(k_scan, dim3(1), dim3(1024), 0, stream, deg, rowptr, n);
    hipMemsetAsync(deg, 0, (size_t)n * sizeof(int), stream);  // reuse as cursor
    hipLaunchKernelGGL(k_scatter, dim3(eb), dim3(256), 0, stream, ei, rowptr, deg, eid, E);
    hipLaunchKernelGGL(k_bsort, dim3(nb), dim3(256), 0, stream, rowptr, eid, n);
    hipLaunchKernelGGL(k_gather, dim3(eb), dim3(256), 0, stream, eid, ei, ea, srcs, eas, E);

    // ---- layer 1 ----
    hipLaunchKernelGGL(k_lin6, dim3((n + 15) / 16), dim3(256), 0, stream,
                       x, n, Wq1, bq1, Wk1, bk1, Wv1, bv1, Ws1, bs1, qb, kb, vb, Bb);
    hipLaunchKernelGGL((k_attn<1>), dim3(wb), dim3(256), 0, stream,
                       qb, kb, vb, rowptr, srcs, eas, uc, uc + HC, Bb, hhi, hlo, n);

    // ---- layer 2 (MFMA GEMM reads hhi/hlo, writes q,k,v + fresh skip into Bb) ----
    hipLaunchKernelGGL(k_lin2, dim3((n + 63) / 64, 4), dim3(256), 0, stream,
                       hhi, hlo, Bph, Bpl, bq2, bk2, bv2, bs2, qb, kb, vb, Bb, n);
    hipLaunchKernelGGL((k_attn<0>), dim3(wb), dim3(256), 0, stream,
                       qb, kb, vb, rowptr, srcs, eas, uc + 2 * HC, uc + 3 * HC, Bb,
                       (unsigned short*)nullptr, (unsigned short*)nullptr, n);

    // ---- fc head ----
    hipLaunchKernelGGL(k_fc, dim3(wb), dim3(256), 0, stream, Bb, Wfc, bfc, (float*)d_out, n);
}

// Round 6
// 398.444 us; speedup vs baseline: 1.2220x; 1.0771x over previous
//
#include <hip/hip_runtime.h>

// TemporalGNN: 2x TransformerConv(H=2, C=64) + edge encoder + fc head.
// Edge encoder is rank-1 (edge_attr is [E,1]): eh_l = ea[e]*u_l + c_l.
// Edge phase: stable counting-sort by dst, then one wave per dst node does
// online-softmax attention with a single output write.
// k/v operand matrices stored as packed bf16 (halves the per-edge gather
// bytes and the GEMM store traffic). Layer-2 linears: split-bf16 MFMA GEMM
// (C = Ah*Bh + Al*Bh + Ah*Bl), B panel in LDS, 2 A-tiles per B fragment
// (3:1 MFMA:ds_read so the LDS pipe is no longer the wave bottleneck).

#define HC 128   // H*C

typedef __attribute__((ext_vector_type(8))) short bf16x8;
typedef __attribute__((ext_vector_type(4))) float f32x4;

__device__ __forceinline__ unsigned bf16_rne(float f) {
    unsigned u = __float_as_uint(f);
    return (u + 0x7fffu + ((u >> 16) & 1u)) >> 16;
}

// ---------- rank-1 edge-encoder precompute ----------
__global__ void k_uc(const float* __restrict__ We_enc, const float* __restrict__ be_enc,
                     const float* __restrict__ We1, const float* __restrict__ We2,
                     float* __restrict__ uc) {
    int c = threadIdx.x;  // 0..127
    float u1 = 0.f, c1 = 0.f, u2 = 0.f, c2 = 0.f;
    for (int j = 0; j < 64; ++j) {
        float we = We_enc[j], be = be_enc[j];
        float w1 = We1[j * HC + c], w2 = We2[j * HC + c];
        u1 += we * w1; c1 += be * w1;
        u2 += we * w2; c2 += be * w2;
    }
    uc[c] = u1; uc[HC + c] = c1; uc[2 * HC + c] = u2; uc[3 * HC + c] = c2;
}

// ---------- pack layer-2 weights to bf16 hi/lo, B^T layout [n=512][k=128] ----------
__global__ __launch_bounds__(256) void k_wpack(
    const float* __restrict__ Wq, const float* __restrict__ Wk,
    const float* __restrict__ Wv, const float* __restrict__ Ws,
    unsigned short* __restrict__ Bph, unsigned short* __restrict__ Bpl) {
    int t = blockIdx.x * 256 + threadIdx.x;   // 0..65535
    int nn = t >> 7;        // 0..511
    int kk = t & 127;
    int mat = nn >> 7, c = nn & 127;
    const float* W = (mat == 0) ? Wq : (mat == 1) ? Wk : (mat == 2) ? Wv : Ws;
    float w = W[kk * 128 + c];
    unsigned hb = bf16_rne(w);
    float hf = __uint_as_float(hb << 16);
    unsigned lb = bf16_rne(w - hf);
    Bph[nn * 128 + kk] = (unsigned short)hb;
    Bpl[nn * 128 + kk] = (unsigned short)lb;
}

// ---------- CSR build (stable counting sort by dst) ----------
__global__ __launch_bounds__(256) void k_hist(const int* __restrict__ ei, int* __restrict__ deg, int E) {
    int t = blockIdx.x * blockDim.x + threadIdx.x;
    if (t < E) atomicAdd(&deg[ei[E + t]], 1);
}

__global__ __launch_bounds__(1024) void k_scan(const int* __restrict__ deg, int* __restrict__ rowptr, int n) {
    __shared__ int part[1024];
    const int tid = threadIdx.x;
    const int per = (n + 1023) / 1024;
    int b = tid * per;
    int e = min(b + per, n);
    int s = 0;
    for (int i = b; i < e; ++i) s += deg[i];
    part[tid] = s;
    __syncthreads();
    for (int off = 1; off < 1024; off <<= 1) {
        int v = (tid >= off) ? part[tid - off] : 0;
        __syncthreads();
        part[tid] += v;
        __syncthreads();
    }
    int run = (tid == 0) ? 0 : part[tid - 1];
    for (int i = b; i < e; ++i) { rowptr[i] = run; run += deg[i]; }
    if (tid == 1023) rowptr[n] = run;
}

__global__ __launch_bounds__(256) void k_scatter(const int* __restrict__ ei, const int* __restrict__ rowptr,
                                                 int* __restrict__ cursor, int* __restrict__ eid, int E) {
    int t = blockIdx.x * blockDim.x + threadIdx.x;
    if (t >= E) return;
    int dst = ei[E + t];
    int pos = rowptr[dst] + atomicAdd(&cursor[dst], 1);
    eid[pos] = t;
}

__global__ __launch_bounds__(256) void k_bsort(const int* __restrict__ rowptr, int* __restrict__ eid, int n) {
    int t = blockIdx.x * blockDim.x + threadIdx.x;
    if (t >= n) return;
    int b = rowptr[t], e = rowptr[t + 1];
    for (int i = b + 1; i < e; ++i) {
        int key = eid[i];
        int j = i - 1;
        while (j >= b && eid[j] > key) { eid[j + 1] = eid[j]; --j; }
        eid[j + 1] = key;
    }
}

__global__ __launch_bounds__(256) void k_gather(const int* __restrict__ eid, const int* __restrict__ ei,
                                                const float* __restrict__ ea,
                                                int* __restrict__ srcs, float* __restrict__ eas, int E) {
    int t = blockIdx.x * blockDim.x + threadIdx.x;
    if (t >= E) return;
    int id = eid[t];
    srcs[t] = ei[id];
    eas[t] = ea[id];
}

// ---------- layer-1 node linears (K=6, vector ALU) ----------
// q,o stored f32; k,v stored packed bf16.
__global__ __launch_bounds__(256) void k_lin6(
    const float* __restrict__ X, int n,
    const float* __restrict__ Wq, const float* __restrict__ bq,
    const float* __restrict__ Wk, const float* __restrict__ bk,
    const float* __restrict__ Wv, const float* __restrict__ bv,
    const float* __restrict__ Ws, const float* __restrict__ bs,
    float* __restrict__ q, unsigned short* __restrict__ k16,
    unsigned short* __restrict__ v16, float* __restrict__ o) {
    __shared__ float xs[16][6];
    const int base = blockIdx.x * 16;
    const int tid = threadIdx.x;
    for (int i = tid; i < 16 * 6; i += 256) {
        int ni = base + i / 6;
        xs[i / 6][i % 6] = (ni < n) ? X[(size_t)ni * 6 + (i % 6)] : 0.f;
    }
    __syncthreads();
    const int c = tid & 127;
    const int m = tid >> 7;  // 0 -> (q,k), 1 -> (v,o)
    const float* WA = m ? Wv : Wq;
    const float* WB = m ? Ws : Wk;
    float accA[16], accB[16];
#pragma unroll
    for (int i = 0; i < 16; ++i) { accA[i] = 0.f; accB[i] = 0.f; }
    for (int j = 0; j < 6; ++j) {
        float w0 = WA[j * HC + c];
        float w1 = WB[j * HC + c];
#pragma unroll
        for (int i = 0; i < 16; ++i) {
            float xv = xs[i][j];
            accA[i] += xv * w0;
            accB[i] += xv * w1;
        }
    }
    if (m == 0) {
        const float bA = bq[c], bB = bk[c];
#pragma unroll
        for (int i = 0; i < 16; ++i) {
            int ni = base + i;
            if (ni < n) {
                q[(size_t)ni * HC + c] = accA[i] + bA;
                k16[(size_t)ni * HC + c] = (unsigned short)bf16_rne(accB[i] + bB);
            }
        }
    } else {
        const float bA = bv[c], bB = bs[c];
#pragma unroll
        for (int i = 0; i < 16; ++i) {
            int ni = base + i;
            if (ni < n) {
                v16[(size_t)ni * HC + c] = (unsigned short)bf16_rne(accA[i] + bA);
                o[(size_t)ni * HC + c] = accB[i] + bB;
            }
        }
    }
}

// ---------- layer-2 node linears: split-bf16 MFMA GEMM, LDS-staged B ----------
// Grid (ceil(n/128), 4). blockIdx.y = col quarter = matrix {q,k,v,s}.
// Block stages that matrix's [128 cols][128 k] hi+lo bf16 panel (64 KB) into
// LDS, then 4 waves x 32 nodes (TWO 16-row A tiles per B fragment: 192 MFMA
// per 64 ds_read_b128 per wave -> MFMA-side bound, not LDS-issue bound).
__global__ __launch_bounds__(256, 2) void k_lin2(
    const unsigned short* __restrict__ hhi, const unsigned short* __restrict__ hlo,
    const unsigned short* __restrict__ Bph, const unsigned short* __restrict__ Bpl,
    const float* __restrict__ bq, const float* __restrict__ bk,
    const float* __restrict__ bv, const float* __restrict__ bs,
    float* __restrict__ q, unsigned short* __restrict__ k16,
    unsigned short* __restrict__ v16, float* __restrict__ o, int n) {
    __shared__ unsigned short Bs[2][128][128];   // 64 KB
    const int tid = threadIdx.x;
    const int cq = blockIdx.y;                   // matrix index
    for (int i = tid; i < 2 * 128 * 16; i += 256) {
        int kk8 = i & 15;
        int nnl = (i >> 4) & 127;
        int h = i >> 11;
        const unsigned short* src = h ? Bpl : Bph;
        bf16x8 val = *(const bf16x8*)&src[((size_t)(cq * 128 + nnl)) * 128 + kk8 * 8];
        int swk = (kk8 ^ (nnl & 7)) * 8;
        *(bf16x8*)&Bs[h][nnl][swk] = val;
    }
    __syncthreads();

    const int wid = tid >> 6, l = tid & 63;
    const int la = l & 15, lk = l >> 4;
    const int mb = blockIdx.x * 128;
    int nodeA0 = mb + wid * 32 + la;
    int nodeA1 = nodeA0 + 16;
    if (nodeA0 >= n) nodeA0 = n - 1;
    if (nodeA1 >= n) nodeA1 = n - 1;
    const int sw = (la & 7) << 3;
    f32x4 acc0[8], acc1[8];
#pragma unroll
    for (int nt = 0; nt < 8; ++nt) {
        acc0[nt] = (f32x4){0.f, 0.f, 0.f, 0.f};
        acc1[nt] = (f32x4){0.f, 0.f, 0.f, 0.f};
    }
#pragma unroll
    for (int ks = 0; ks < 4; ++ks) {
        const int koff = lk * 8 + ks * 32;
        bf16x8 Ah0 = *(const bf16x8*)&hhi[(size_t)nodeA0 * 128 + koff];
        bf16x8 Al0 = *(const bf16x8*)&hlo[(size_t)nodeA0 * 128 + koff];
        bf16x8 Ah1 = *(const bf16x8*)&hhi[(size_t)nodeA1 * 128 + koff];
        bf16x8 Al1 = *(const bf16x8*)&hlo[(size_t)nodeA1 * 128 + koff];
        const int rk = koff ^ sw;
#pragma unroll
        for (int nt = 0; nt < 8; ++nt) {
            const int nnl = nt * 16 + la;
            bf16x8 Bh = *(const bf16x8*)&Bs[0][nnl][rk];
            bf16x8 Bl = *(const bf16x8*)&Bs[1][nnl][rk];
            acc0[nt] = __builtin_amdgcn_mfma_f32_16x16x32_bf16(Ah0, Bh, acc0[nt], 0, 0, 0);
            acc1[nt] = __builtin_amdgcn_mfma_f32_16x16x32_bf16(Ah1, Bh, acc1[nt], 0, 0, 0);
            acc0[nt] = __builtin_amdgcn_mfma_f32_16x16x32_bf16(Al0, Bh, acc0[nt], 0, 0, 0);
            acc1[nt] = __builtin_amdgcn_mfma_f32_16x16x32_bf16(Al1, Bh, acc1[nt], 0, 0, 0);
            acc0[nt] = __builtin_amdgcn_mfma_f32_16x16x32_bf16(Ah0, Bl, acc0[nt], 0, 0, 0);
            acc1[nt] = __builtin_amdgcn_mfma_f32_16x16x32_bf16(Ah1, Bl, acc1[nt], 0, 0, 0);
        }
    }
    const float* bias = (cq == 0) ? bq : (cq == 1) ? bk : (cq == 2) ? bv : bs;
    const int crow0 = mb + wid * 32 + lk * 4;
#pragma unroll
    for (int nt = 0; nt < 8; ++nt) {
        const int col = nt * 16 + la;
        const float bb = bias[col];
        if (cq == 0 || cq == 3) {
            float* out = (cq == 0) ? q : o;
#pragma unroll
            for (int j = 0; j < 4; ++j) {
                int n0 = crow0 + j;
                if (n0 < n) out[(size_t)n0 * 128 + col] = acc0[nt][j] + bb;
                int n1 = n0 + 16;
                if (n1 < n) out[(size_t)n1 * 128 + col] = acc1[nt][j] + bb;
            }
        } else {
            unsigned short* out = (cq == 1) ? k16 : v16;
#pragma unroll
            for (int j = 0; j < 4; ++j) {
                int n0 = crow0 + j;
                if (n0 < n) out[(size_t)n0 * 128 + col] = (unsigned short)bf16_rne(acc0[nt][j] + bb);
                int n1 = n0 + 16;
                if (n1 < n) out[(size_t)n1 * 128 + col] = (unsigned short)bf16_rne(acc1[nt][j] + bb);
            }
        }
    }
}

// ---------- fused online-softmax attention, one wave per dst node ----------
// Lane l holds channels {2l, 2l+1}; lanes 0..31 = head0, 32..63 = head1.
// k/v gathered as packed bf16 (one uint per lane per row).
// MODE 1 (layer 1): out = relu(attn + skip), stored as bf16 hi/lo pair only.
// MODE 0 (layer 2): out = attn + skip, stored f32 into io.
template <int MODE>
__global__ __launch_bounds__(256) void k_attn(
    const float* __restrict__ q, const unsigned int* __restrict__ k16,
    const unsigned int* __restrict__ v16,
    const int* __restrict__ rowptr, const int* __restrict__ srcs, const float* __restrict__ eas,
    const float* __restrict__ ucu, const float* __restrict__ ucc,
    float* __restrict__ io, unsigned short* __restrict__ hhi, unsigned short* __restrict__ hlo,
    int n) {
    int wid = (int)((blockIdx.x * (size_t)blockDim.x + threadIdx.x) >> 6);
    int lane = threadIdx.x & 63;
    if (wid >= n) return;
    const float2* q2 = (const float2*)q;
    float2 qr = q2[(size_t)wid * 64 + lane];
    float2 uu = ((const float2*)ucu)[lane];
    float2 cc = ((const float2*)ucc)[lane];
    int b = rowptr[wid], e = rowptr[wid + 1];
    float m = -INFINITY, s = 0.f;
    float ax = 0.f, ay = 0.f;
    for (int p = b; p < e; ++p) {
        int src = srcs[p];
        float eav = eas[p];
        unsigned int ku = k16[(size_t)src * 64 + lane];
        unsigned int vu = v16[(size_t)src * 64 + lane];
        float krx = __uint_as_float(ku << 16);
        float kry = __uint_as_float(ku & 0xffff0000u);
        float vrx = __uint_as_float(vu << 16);
        float vry = __uint_as_float(vu & 0xffff0000u);
        float eh0 = eav * uu.x + cc.x;
        float eh1 = eav * uu.y + cc.y;
        float d = qr.x * (krx + eh0) + qr.y * (kry + eh1);
        d += __shfl_xor(d, 1); d += __shfl_xor(d, 2); d += __shfl_xor(d, 4);
        d += __shfl_xor(d, 8); d += __shfl_xor(d, 16);   // per-head (32-lane) sum
        float a = d * 0.125f;                            // / sqrt(64)
        float nm = fmaxf(m, a);
        float sc = __expf(m - nm);
        float pw = __expf(a - nm);
        s = s * sc + pw;
        ax = ax * sc + pw * (vrx + eh0);
        ay = ay * sc + pw * (vry + eh1);
        m = nm;
    }
    float inv = 1.f / (s + 1e-16f);
    float2 skip = ((const float2*)io)[(size_t)wid * 64 + lane];
    float o0 = ax * inv + skip.x;
    float o1 = ay * inv + skip.y;
    if (MODE == 1) {
        o0 = fmaxf(o0, 0.f); o1 = fmaxf(o1, 0.f);
        unsigned h0 = bf16_rne(o0);
        unsigned h1 = bf16_rne(o1);
        float r0 = o0 - __uint_as_float(h0 << 16);
        float r1 = o1 - __uint_as_float(h1 << 16);
        unsigned l0 = bf16_rne(r0);
        unsigned l1 = bf16_rne(r1);
        ushort2* ph = (ushort2*)&hhi[(size_t)wid * 128 + 2 * lane];
        ushort2* pl = (ushort2*)&hlo[(size_t)wid * 128 + 2 * lane];
        *ph = make_ushort2((unsigned short)h0, (unsigned short)h1);
        *pl = make_ushort2((unsigned short)l0, (unsigned short)l1);
    } else {
        ((float2*)io)[(size_t)wid * 64 + lane] = make_float2(o0, o1);
    }
}

// ---------- fc head (relu fused), one wave per node ----------
__global__ __launch_bounds__(256) void k_fc(
    const float* __restrict__ h, const float* __restrict__ Wfc,
    const float* __restrict__ bfc, float* __restrict__ out, int n) {
    int w = (int)((blockIdx.x * (size_t)blockDim.x + threadIdx.x) >> 6);
    int lane = threadIdx.x & 63;
    if (w >= n) return;
    const float2* h2 = (const float2*)h;
    const float2* w2 = (const float2*)Wfc;
    float2 hv = h2[(size_t)w * 64 + lane];
    float2 wv = w2[lane];
    float vsum = fmaxf(hv.x, 0.f) * wv.x + fmaxf(hv.y, 0.f) * wv.y;
#pragma unroll
    for (int off = 1; off < 64; off <<= 1) vsum += __shfl_xor(vsum, off);
    if (lane == 0) out[w] = vsum + bfc[0];
}

extern "C" void kernel_launch(void* const* d_in, const int* in_sizes, int n_in,
                              void* d_out, int out_size, void* d_ws, size_t ws_size,
                              hipStream_t stream) {
    const float* x      = (const float*)d_in[0];
    const int*   ei     = (const int*)d_in[1];
    const float* ea     = (const float*)d_in[2];
    const float* We_enc = (const float*)d_in[3];
    const float* be_enc = (const float*)d_in[4];
    const float* Wq1 = (const float*)d_in[5],  *bq1 = (const float*)d_in[6];
    const float* Wk1 = (const float*)d_in[7],  *bk1 = (const float*)d_in[8];
    const float* Wv1 = (const float*)d_in[9],  *bv1 = (const float*)d_in[10];
    const float* We1 = (const float*)d_in[11];
    const float* Ws1 = (const float*)d_in[12], *bs1 = (const float*)d_in[13];
    const float* Wq2 = (const float*)d_in[14], *bq2 = (const float*)d_in[15];
    const float* Wk2 = (const float*)d_in[16], *bk2 = (const float*)d_in[17];
    const float* Wv2 = (const float*)d_in[18], *bv2 = (const float*)d_in[19];
    const float* We2 = (const float*)d_in[20];
    const float* Ws2 = (const float*)d_in[21], *bs2 = (const float*)d_in[22];
    const float* Wfc = (const float*)d_in[23], *bfc = (const float*)d_in[24];

    const int n = in_sizes[0] / 6;   // 50000
    const int E = in_sizes[2];       // 409600

    float* ws = (float*)d_ws;
    size_t off = 0;
    float* qb = ws + off; off += (size_t)n * HC;
    float* Bb = ws + off; off += (size_t)n * HC;   // skip-init / h buffer
    unsigned short* kb16 = (unsigned short*)(ws + off); off += (size_t)n * HC / 2;
    unsigned short* vb16 = (unsigned short*)(ws + off); off += (size_t)n * HC / 2;
    int* rowptr = (int*)(ws + off); off += (size_t)(n + 1);
    int* deg    = (int*)(ws + off); off += (size_t)n;   // also scatter cursor
    int* eid    = (int*)(ws + off); off += (size_t)E;
    int* srcs   = (int*)(ws + off); off += (size_t)E;
    float* eas  = ws + off; off += (size_t)E;
    float* uc   = ws + off; off += 512;
    unsigned short* hhi = (unsigned short*)(ws + off); off += (size_t)n * HC / 2;
    unsigned short* hlo = (unsigned short*)(ws + off); off += (size_t)n * HC / 2;
    unsigned short* Bph = (unsigned short*)(ws + off); off += 512 * 128 / 2;
    unsigned short* Bpl = (unsigned short*)(ws + off); off += 512 * 128 / 2;

    const int eb = (E + 255) / 256;
    const int nb = (n + 255) / 256;
    const int wb = (int)(((size_t)n * 64 + 255) / 256);

    hipLaunchKernelGGL(k_uc, dim3(1), dim3(128), 0, stream, We_enc, be_enc, We1, We2, uc);
    hipLaunchKernelGGL(k_wpack, dim3(256), dim3(256), 0, stream, Wq2, Wk2, Wv2, Ws2, Bph, Bpl);

    // ---- CSR build (shared by both layers) ----
    hipMemsetAsync(deg, 0, (size_t)n * sizeof(int), stream);
    hipLaunchKernelGGL(k_hist, dim3(eb), dim3(256), 0, stream, ei, deg, E);
    hipLaunchKernelGGL(k_scan, dim3(1), dim3(1024), 0, stream, deg, rowptr, n);
    hipMemsetAsync(deg, 0, (size_t)n * sizeof(int), stream);  // reuse as cursor
    hipLaunchKernelGGL(k_scatter, dim3(eb), dim3(256), 0, stream, ei, rowptr, deg, eid, E);
    hipLaunchKernelGGL(k_bsort, dim3(nb), dim3(256), 0, stream, rowptr, eid, n);
    hipLaunchKernelGGL(k_gather, dim3(eb), dim3(256), 0, stream, eid, ei, ea, srcs, eas, E);

    // ---- layer 1 ----
    hipLaunchKernelGGL(k_lin6, dim3((n + 15) / 16), dim3(256), 0, stream,
                       x, n, Wq1, bq1, Wk1, bk1, Wv1, bv1, Ws1, bs1, qb, kb16, vb16, Bb);
    hipLaunchKernelGGL((k_attn<1>), dim3(wb), dim3(256), 0, stream,
                       qb, (const unsigned int*)kb16, (const unsigned int*)vb16,
                       rowptr, srcs, eas, uc, uc + HC, Bb, hhi, hlo, n);

    // ---- layer 2 (MFMA GEMM reads hhi/hlo; writes q f32, k/v bf16, skip into Bb) ----
    hipLaunchKernelGGL(k_lin2, dim3((n + 127) / 128, 4), dim3(256), 0, stream,
                       hhi, hlo, Bph, Bpl, bq2, bk2, bv2, bs2, qb, kb16, vb16, Bb, n);
    hipLaunchKernelGGL((k_attn<0>), dim3(wb), dim3(256), 0, stream,
                       qb, (const unsigned int*)kb16, (const unsigned int*)vb16,
                       rowptr, srcs, eas, uc + 2 * HC, uc + 3 * HC, Bb,
                       (unsigned short*)nullptr, (unsigned short*)nullptr, n);

    // ---- fc head ----
    hipLaunchKernelGGL(k_fc, dim3(wb), dim3(256), 0, stream, Bb, Wfc, bfc, (float*)d_out, n);
}

// Round 7
// 361.885 us; speedup vs baseline: 1.3455x; 1.1010x over previous
//
#include <hip/hip_runtime.h>

// TemporalGNN: 2x TransformerConv(H=2, C=64) + edge encoder + fc head.
// Edge encoder is rank-1 (edge_attr is [E,1]): eh_l = ea[e]*u_l + c_l.
// Edge phase: stable counting-sort by dst, then one wave per dst node does
// online-softmax attention (k/v gathered as packed bf16 from one interleaved
// row per node, next-edge software prefetch).
// Layer-2 linears: MFMA GEMM with split-bf16 A (hi+lo) x single-bf16 B.
// B panel (32 KB) in LDS -> 4-5 blocks/CU (R6 was latency-bound at 2
// blocks/CU with the 64 KB double-panel).

#define HC 128   // H*C

typedef __attribute__((ext_vector_type(8))) short bf16x8;
typedef __attribute__((ext_vector_type(4))) float f32x4;

__device__ __forceinline__ unsigned bf16_rne(float f) {
    unsigned u = __float_as_uint(f);
    return (u + 0x7fffu + ((u >> 16) & 1u)) >> 16;
}

// ---------- rank-1 edge-encoder precompute ----------
__global__ void k_uc(const float* __restrict__ We_enc, const float* __restrict__ be_enc,
                     const float* __restrict__ We1, const float* __restrict__ We2,
                     float* __restrict__ uc) {
    int c = threadIdx.x;  // 0..127
    float u1 = 0.f, c1 = 0.f, u2 = 0.f, c2 = 0.f;
    for (int j = 0; j < 64; ++j) {
        float we = We_enc[j], be = be_enc[j];
        float w1 = We1[j * HC + c], w2 = We2[j * HC + c];
        u1 += we * w1; c1 += be * w1;
        u2 += we * w2; c2 += be * w2;
    }
    uc[c] = u1; uc[HC + c] = c1; uc[2 * HC + c] = u2; uc[3 * HC + c] = c2;
}

// ---------- pack layer-2 weights to bf16, B^T layout [n=512][k=128] ----------
__global__ __launch_bounds__(256) void k_wpack(
    const float* __restrict__ Wq, const float* __restrict__ Wk,
    const float* __restrict__ Wv, const float* __restrict__ Ws,
    unsigned short* __restrict__ Bph) {
    int t = blockIdx.x * 256 + threadIdx.x;   // 0..65535
    int nn = t >> 7;        // 0..511
    int kk = t & 127;
    int mat = nn >> 7, c = nn & 127;
    const float* W = (mat == 0) ? Wq : (mat == 1) ? Wk : (mat == 2) ? Wv : Ws;
    Bph[nn * 128 + kk] = (unsigned short)bf16_rne(W[kk * 128 + c]);
}

// ---------- CSR build (stable counting sort by dst) ----------
__global__ __launch_bounds__(256) void k_hist(const int* __restrict__ ei, int* __restrict__ deg, int E) {
    int t = blockIdx.x * blockDim.x + threadIdx.x;
    if (t < E) atomicAdd(&deg[ei[E + t]], 1);
}

__global__ __launch_bounds__(1024) void k_scan(const int* __restrict__ deg, int* __restrict__ rowptr, int n) {
    __shared__ int part[1024];
    const int tid = threadIdx.x;
    const int per = (n + 1023) / 1024;
    int b = tid * per;
    int e = min(b + per, n);
    int s = 0;
    for (int i = b; i < e; ++i) s += deg[i];
    part[tid] = s;
    __syncthreads();
    for (int off = 1; off < 1024; off <<= 1) {
        int v = (tid >= off) ? part[tid - off] : 0;
        __syncthreads();
        part[tid] += v;
        __syncthreads();
    }
    int run = (tid == 0) ? 0 : part[tid - 1];
    for (int i = b; i < e; ++i) { rowptr[i] = run; run += deg[i]; }
    if (tid == 1023) rowptr[n] = run;
}

__global__ __launch_bounds__(256) void k_scatter(const int* __restrict__ ei, const int* __restrict__ rowptr,
                                                 int* __restrict__ cursor, int* __restrict__ eid, int E) {
    int t = blockIdx.x * blockDim.x + threadIdx.x;
    if (t >= E) return;
    int dst = ei[E + t];
    int pos = rowptr[dst] + atomicAdd(&cursor[dst], 1);
    eid[pos] = t;
}

__global__ __launch_bounds__(256) void k_bsort(const int* __restrict__ rowptr, int* __restrict__ eid, int n) {
    int t = blockIdx.x * blockDim.x + threadIdx.x;
    if (t >= n) return;
    int b = rowptr[t], e = rowptr[t + 1];
    for (int i = b + 1; i < e; ++i) {
        int key = eid[i];
        int j = i - 1;
        while (j >= b && eid[j] > key) { eid[j + 1] = eid[j]; --j; }
        eid[j + 1] = key;
    }
}

__global__ __launch_bounds__(256) void k_gather(const int* __restrict__ eid, const int* __restrict__ ei,
                                                const float* __restrict__ ea,
                                                int* __restrict__ srcs, float* __restrict__ eas, int E) {
    int t = blockIdx.x * blockDim.x + threadIdx.x;
    if (t >= E) return;
    int id = eid[t];
    srcs[t] = ei[id];
    eas[t] = ea[id];
}

// ---------- layer-1 node linears (K=6, vector ALU) ----------
// q,o stored f32; k,v stored packed bf16 into interleaved kv rows [256 ushort].
__global__ __launch_bounds__(256) void k_lin6(
    const float* __restrict__ X, int n,
    const float* __restrict__ Wq, const float* __restrict__ bq,
    const float* __restrict__ Wk, const float* __restrict__ bk,
    const float* __restrict__ Wv, const float* __restrict__ bv,
    const float* __restrict__ Ws, const float* __restrict__ bs,
    float* __restrict__ q, unsigned short* __restrict__ kv,
    float* __restrict__ o) {
    __shared__ float xs[16][6];
    const int base = blockIdx.x * 16;
    const int tid = threadIdx.x;
    for (int i = tid; i < 16 * 6; i += 256) {
        int ni = base + i / 6;
        xs[i / 6][i % 6] = (ni < n) ? X[(size_t)ni * 6 + (i % 6)] : 0.f;
    }
    __syncthreads();
    const int c = tid & 127;
    const int m = tid >> 7;  // 0 -> (q,k), 1 -> (v,o)
    const float* WA = m ? Wv : Wq;
    const float* WB = m ? Ws : Wk;
    float accA[16], accB[16];
#pragma unroll
    for (int i = 0; i < 16; ++i) { accA[i] = 0.f; accB[i] = 0.f; }
    for (int j = 0; j < 6; ++j) {
        float w0 = WA[j * HC + c];
        float w1 = WB[j * HC + c];
#pragma unroll
        for (int i = 0; i < 16; ++i) {
            float xv = xs[i][j];
            accA[i] += xv * w0;
            accB[i] += xv * w1;
        }
    }
    if (m == 0) {
        const float bA = bq[c], bB = bk[c];
#pragma unroll
        for (int i = 0; i < 16; ++i) {
            int ni = base + i;
            if (ni < n) {
                q[(size_t)ni * HC + c] = accA[i] + bA;
                kv[(size_t)ni * 256 + c] = (unsigned short)bf16_rne(accB[i] + bB);
            }
        }
    } else {
        const float bA = bv[c], bB = bs[c];
#pragma unroll
        for (int i = 0; i < 16; ++i) {
            int ni = base + i;
            if (ni < n) {
                kv[(size_t)ni * 256 + 128 + c] = (unsigned short)bf16_rne(accA[i] + bA);
                o[(size_t)ni * HC + c] = accB[i] + bB;
            }
        }
    }
}

// ---------- layer-2 node linears: split-A bf16 MFMA GEMM, LDS-staged bf16 B ----------
// Grid (ceil(n/128), 4). blockIdx.y = col quarter = matrix {q,k,v,s}.
// Block stages that matrix's [128 cols][128 k] bf16 panel (32 KB) into LDS;
// 4 waves x 32 nodes; per B fragment: 4 MFMAs (2 A-tiles x (Ah+Al)).
// 32 KB LDS + <=128 VGPR -> 4 blocks/CU (R6 was stuck at 2 -> latency-bound).
__global__ __launch_bounds__(256, 4) void k_lin2(
    const unsigned short* __restrict__ hhi, const unsigned short* __restrict__ hlo,
    const unsigned short* __restrict__ Bph,
    const float* __restrict__ bq, const float* __restrict__ bk,
    const float* __restrict__ bv, const float* __restrict__ bs,
    float* __restrict__ q, unsigned short* __restrict__ kv,
    float* __restrict__ o, int n) {
    __shared__ unsigned short Bs[128][128];   // 32 KB
    const int tid = threadIdx.x;
    const int cq = blockIdx.y;                // matrix index
    for (int i = tid; i < 128 * 16; i += 256) {
        int kk8 = i & 15;
        int nnl = i >> 4;
        bf16x8 val = *(const bf16x8*)&Bph[((size_t)(cq * 128 + nnl)) * 128 + kk8 * 8];
        int swk = (kk8 ^ (nnl & 7)) * 8;
        *(bf16x8*)&Bs[nnl][swk] = val;
    }
    __syncthreads();

    const int wid = tid >> 6, l = tid & 63;
    const int la = l & 15, lk = l >> 4;
    const int mb = blockIdx.x * 128;
    int nodeA0 = mb + wid * 32 + la;
    int nodeA1 = nodeA0 + 16;
    if (nodeA0 >= n) nodeA0 = n - 1;
    if (nodeA1 >= n) nodeA1 = n - 1;
    const int sw = (la & 7) << 3;
    f32x4 acc0[8], acc1[8];
#pragma unroll
    for (int nt = 0; nt < 8; ++nt) {
        acc0[nt] = (f32x4){0.f, 0.f, 0.f, 0.f};
        acc1[nt] = (f32x4){0.f, 0.f, 0.f, 0.f};
    }
    // double-buffered A fragments (static indices via full unroll)
    bf16x8 a0h[2], a0l[2], a1h[2], a1l[2];
    {
        const int ko = lk * 8;
        a0h[0] = *(const bf16x8*)&hhi[(size_t)nodeA0 * 128 + ko];
        a0l[0] = *(const bf16x8*)&hlo[(size_t)nodeA0 * 128 + ko];
        a1h[0] = *(const bf16x8*)&hhi[(size_t)nodeA1 * 128 + ko];
        a1l[0] = *(const bf16x8*)&hlo[(size_t)nodeA1 * 128 + ko];
    }
#pragma unroll
    for (int ks = 0; ks < 4; ++ks) {
        const int cur = ks & 1, nxt = cur ^ 1;
        if (ks < 3) {
            const int ko = lk * 8 + (ks + 1) * 32;
            a0h[nxt] = *(const bf16x8*)&hhi[(size_t)nodeA0 * 128 + ko];
            a0l[nxt] = *(const bf16x8*)&hlo[(size_t)nodeA0 * 128 + ko];
            a1h[nxt] = *(const bf16x8*)&hhi[(size_t)nodeA1 * 128 + ko];
            a1l[nxt] = *(const bf16x8*)&hlo[(size_t)nodeA1 * 128 + ko];
        }
        const int rk = (lk * 8 + ks * 32) ^ sw;
#pragma unroll
        for (int nt = 0; nt < 8; ++nt) {
            bf16x8 Bh = *(const bf16x8*)&Bs[nt * 16 + la][rk];
            acc0[nt] = __builtin_amdgcn_mfma_f32_16x16x32_bf16(a0h[cur], Bh, acc0[nt], 0, 0, 0);
            acc0[nt] = __builtin_amdgcn_mfma_f32_16x16x32_bf16(a0l[cur], Bh, acc0[nt], 0, 0, 0);
            acc1[nt] = __builtin_amdgcn_mfma_f32_16x16x32_bf16(a1h[cur], Bh, acc1[nt], 0, 0, 0);
            acc1[nt] = __builtin_amdgcn_mfma_f32_16x16x32_bf16(a1l[cur], Bh, acc1[nt], 0, 0, 0);
        }
    }
    const float* bias = (cq == 0) ? bq : (cq == 1) ? bk : (cq == 2) ? bv : bs;
    const int crow0 = mb + wid * 32 + lk * 4;
#pragma unroll
    for (int nt = 0; nt < 8; ++nt) {
        const int col = nt * 16 + la;
        const float bb = bias[col];
        if (cq == 0 || cq == 3) {
            float* out = (cq == 0) ? q : o;
#pragma unroll
            for (int j = 0; j < 4; ++j) {
                int n0 = crow0 + j;
                if (n0 < n) out[(size_t)n0 * 128 + col] = acc0[nt][j] + bb;
                int n1 = n0 + 16;
                if (n1 < n) out[(size_t)n1 * 128 + col] = acc1[nt][j] + bb;
            }
        } else {
            const int co = (cq == 1) ? col : 128 + col;
#pragma unroll
            for (int j = 0; j < 4; ++j) {
                int n0 = crow0 + j;
                if (n0 < n) kv[(size_t)n0 * 256 + co] = (unsigned short)bf16_rne(acc0[nt][j] + bb);
                int n1 = n0 + 16;
                if (n1 < n) kv[(size_t)n1 * 256 + co] = (unsigned short)bf16_rne(acc1[nt][j] + bb);
            }
        }
    }
}

// ---------- fused online-softmax attention, one wave per dst node ----------
// Lane l holds channels {2l, 2l+1}; lanes 0..31 = head0, 32..63 = head1.
// k/v gathered from one interleaved bf16 row per src node, with next-edge
// software prefetch. MODE 1: relu(attn+skip) -> bf16 hi/lo. MODE 0: f32 io.
template <int MODE>
__global__ __launch_bounds__(256) void k_attn(
    const float* __restrict__ q, const unsigned int* __restrict__ kvp,
    const int* __restrict__ rowptr, const int* __restrict__ srcs, const float* __restrict__ eas,
    const float* __restrict__ ucu, const float* __restrict__ ucc,
    float* __restrict__ io, unsigned short* __restrict__ hhi, unsigned short* __restrict__ hlo,
    int n) {
    int wid = (int)((blockIdx.x * (size_t)blockDim.x + threadIdx.x) >> 6);
    int lane = threadIdx.x & 63;
    if (wid >= n) return;
    const float2* q2 = (const float2*)q;
    float2 qr = q2[(size_t)wid * 64 + lane];
    float2 uu = ((const float2*)ucu)[lane];
    float2 cc = ((const float2*)ucc)[lane];
    int b = rowptr[wid], e = rowptr[wid + 1];
    float m = -INFINITY, s = 0.f;
    float ax = 0.f, ay = 0.f;
    if (b < e) {
        int src = srcs[b];
        float eav = eas[b];
        unsigned ku = kvp[(size_t)src * 128 + lane];
        unsigned vu = kvp[(size_t)src * 128 + 64 + lane];
        for (int p = b; p < e; ++p) {
            // prefetch next edge (clamped; redundant load on last iter)
            int pn = (p + 1 < e) ? p + 1 : p;
            int srcn = srcs[pn];
            float eavn = eas[pn];
            unsigned kun = kvp[(size_t)srcn * 128 + lane];
            unsigned vun = kvp[(size_t)srcn * 128 + 64 + lane];

            float krx = __uint_as_float(ku << 16);
            float kry = __uint_as_float(ku & 0xffff0000u);
            float vrx = __uint_as_float(vu << 16);
            float vry = __uint_as_float(vu & 0xffff0000u);
            float eh0 = eav * uu.x + cc.x;
            float eh1 = eav * uu.y + cc.y;
            float d = qr.x * (krx + eh0) + qr.y * (kry + eh1);
            d += __shfl_xor(d, 1); d += __shfl_xor(d, 2); d += __shfl_xor(d, 4);
            d += __shfl_xor(d, 8); d += __shfl_xor(d, 16);   // per-head sum
            float a = d * 0.125f;                            // / sqrt(64)
            float nm = fmaxf(m, a);
            float sc = __expf(m - nm);
            float pw = __expf(a - nm);
            s = s * sc + pw;
            ax = ax * sc + pw * (vrx + eh0);
            ay = ay * sc + pw * (vry + eh1);
            m = nm;
            ku = kun; vu = vun; eav = eavn;
        }
    }
    float inv = 1.f / (s + 1e-16f);
    float2 skip = ((const float2*)io)[(size_t)wid * 64 + lane];
    float o0 = ax * inv + skip.x;
    float o1 = ay * inv + skip.y;
    if (MODE == 1) {
        o0 = fmaxf(o0, 0.f); o1 = fmaxf(o1, 0.f);
        unsigned h0 = bf16_rne(o0);
        unsigned h1 = bf16_rne(o1);
        float r0 = o0 - __uint_as_float(h0 << 16);
        float r1 = o1 - __uint_as_float(h1 << 16);
        unsigned l0 = bf16_rne(r0);
        unsigned l1 = bf16_rne(r1);
        ushort2* ph = (ushort2*)&hhi[(size_t)wid * 128 + 2 * lane];
        ushort2* pl = (ushort2*)&hlo[(size_t)wid * 128 + 2 * lane];
        *ph = make_ushort2((unsigned short)h0, (unsigned short)h1);
        *pl = make_ushort2((unsigned short)l0, (unsigned short)l1);
    } else {
        ((float2*)io)[(size_t)wid * 64 + lane] = make_float2(o0, o1);
    }
}

// ---------- fc head (relu fused), one wave per node ----------
__global__ __launch_bounds__(256) void k_fc(
    const float* __restrict__ h, const float* __restrict__ Wfc,
    const float* __restrict__ bfc, float* __restrict__ out, int n) {
    int w = (int)((blockIdx.x * (size_t)blockDim.x + threadIdx.x) >> 6);
    int lane = threadIdx.x & 63;
    if (w >= n) return;
    const float2* h2 = (const float2*)h;
    const float2* w2 = (const float2*)Wfc;
    float2 hv = h2[(size_t)w * 64 + lane];
    float2 wv = w2[lane];
    float vsum = fmaxf(hv.x, 0.f) * wv.x + fmaxf(hv.y, 0.f) * wv.y;
#pragma unroll
    for (int off = 1; off < 64; off <<= 1) vsum += __shfl_xor(vsum, off);
    if (lane == 0) out[w] = vsum + bfc[0];
}

extern "C" void kernel_launch(void* const* d_in, const int* in_sizes, int n_in,
                              void* d_out, int out_size, void* d_ws, size_t ws_size,
                              hipStream_t stream) {
    const float* x      = (const float*)d_in[0];
    const int*   ei     = (const int*)d_in[1];
    const float* ea     = (const float*)d_in[2];
    const float* We_enc = (const float*)d_in[3];
    const float* be_enc = (const float*)d_in[4];
    const float* Wq1 = (const float*)d_in[5],  *bq1 = (const float*)d_in[6];
    const float* Wk1 = (const float*)d_in[7],  *bk1 = (const float*)d_in[8];
    const float* Wv1 = (const float*)d_in[9],  *bv1 = (const float*)d_in[10];
    const float* We1 = (const float*)d_in[11];
    const float* Ws1 = (const float*)d_in[12], *bs1 = (const float*)d_in[13];
    const float* Wq2 = (const float*)d_in[14], *bq2 = (const float*)d_in[15];
    const float* Wk2 = (const float*)d_in[16], *bk2 = (const float*)d_in[17];
    const float* Wv2 = (const float*)d_in[18], *bv2 = (const float*)d_in[19];
    const float* We2 = (const float*)d_in[20];
    const float* Ws2 = (const float*)d_in[21], *bs2 = (const float*)d_in[22];
    const float* Wfc = (const float*)d_in[23], *bfc = (const float*)d_in[24];

    const int n = in_sizes[0] / 6;   // 50000
    const int E = in_sizes[2];       // 409600

    float* ws = (float*)d_ws;
    size_t off = 0;
    float* qb = ws + off; off += (size_t)n * HC;
    float* Bb = ws + off; off += (size_t)n * HC;   // skip-init / h buffer
    unsigned short* kv16 = (unsigned short*)(ws + off); off += (size_t)n * HC;  // interleaved k|v bf16
    int* rowptr = (int*)(ws + off); off += (size_t)(n + 1);
    int* deg    = (int*)(ws + off); off += (size_t)n;   // also scatter cursor
    int* eid    = (int*)(ws + off); off += (size_t)E;
    int* srcs   = (int*)(ws + off); off += (size_t)E;
    float* eas  = ws + off; off += (size_t)E;
    float* uc   = ws + off; off += 512;
    unsigned short* hhi = (unsigned short*)(ws + off); off += (size_t)n * HC / 2;
    unsigned short* hlo = (unsigned short*)(ws + off); off += (size_t)n * HC / 2;
    unsigned short* Bph = (unsigned short*)(ws + off); off += 512 * 128 / 2;

    const int eb = (E + 255) / 256;
    const int nb = (n + 255) / 256;
    const int wb = (int)(((size_t)n * 64 + 255) / 256);

    hipLaunchKernelGGL(k_uc, dim3(1), dim3(128), 0, stream, We_enc, be_enc, We1, We2, uc);
    hipLaunchKernelGGL(k_wpack, dim3(256), dim3(256), 0, stream, Wq2, Wk2, Wv2, Ws2, Bph);

    // ---- CSR build (shared by both layers) ----
    hipMemsetAsync(deg, 0, (size_t)n * sizeof(int), stream);
    hipLaunchKernelGGL(k_hist, dim3(eb), dim3(256), 0, stream, ei, deg, E);
    hipLaunchKernelGGL(k_scan, dim3(1), dim3(1024), 0, stream, deg, rowptr, n);
    hipMemsetAsync(deg, 0, (size_t)n * sizeof(int), stream);  // reuse as cursor
    hipLaunchKernelGGL(k_scatter, dim3(eb), dim3(256), 0, stream, ei, rowptr, deg, eid, E);
    hipLaunchKernelGGL(k_bsort, dim3(nb), dim3(256), 0, stream, rowptr, eid, n);
    hipLaunchKernelGGL(k_gather, dim3(eb), dim3(256), 0, stream, eid, ei, ea, srcs, eas, E);

    // ---- layer 1 ----
    hipLaunchKernelGGL(k_lin6, dim3((n + 15) / 16), dim3(256), 0, stream,
                       x, n, Wq1, bq1, Wk1, bk1, Wv1, bv1, Ws1, bs1, qb, kv16, Bb);
    hipLaunchKernelGGL((k_attn<1>), dim3(wb), dim3(256), 0, stream,
                       qb, (const unsigned int*)kv16,
                       rowptr, srcs, eas, uc, uc + HC, Bb, hhi, hlo, n);

    // ---- layer 2 (MFMA GEMM reads hhi/hlo; writes q f32, k/v bf16, skip into Bb) ----
    hipLaunchKernelGGL(k_lin2, dim3((n + 127) / 128, 4), dim3(256), 0, stream,
                       hhi, hlo, Bph, bq2, bk2, bv2, bs2, qb, kv16, Bb, n);
    hipLaunchKernelGGL((k_attn<0>), dim3(wb), dim3(256), 0, stream,
                       qb, (const unsigned int*)kv16,
                       rowptr, srcs, eas, uc + 2 * HC, uc + 3 * HC, Bb,
                       (unsigned short*)nullptr, (unsigned short*)nullptr, n);

    // ---- fc head ----
    hipLaunchKernelGGL(k_fc, dim3(wb), dim3(256), 0, stream, Bb, Wfc, bfc, (float*)d_out, n);
}

// Round 8
// 294.446 us; speedup vs baseline: 1.6537x; 1.2290x over previous
//
#include <hip/hip_runtime.h>

// TemporalGNN: 2x TransformerConv(H=2, C=64) + edge encoder + fc head.
// Edge encoder is rank-1 (edge_attr is [E,1]): eh_l = ea[e]*u_l + c_l.
// Edge phase: stable counting-sort by dst, then one wave per dst node does
// online-softmax attention (k/v gathered as packed bf16 from one interleaved
// row per node, next-edge software prefetch).
// Layer-2 linears: MFMA GEMM with split-bf16 A (hi+lo) x single-bf16 B,
// 32 KB LDS B panel, 4 blocks/CU.
// CSR scan: 3-pass hierarchical (R7's single-WG scan was 78us of pure
// single-CU latency -- 22% of total runtime).

#define HC 128   // H*C

typedef __attribute__((ext_vector_type(8))) short bf16x8;
typedef __attribute__((ext_vector_type(4))) float f32x4;

__device__ __forceinline__ unsigned bf16_rne(float f) {
    unsigned u = __float_as_uint(f);
    return (u + 0x7fffu + ((u >> 16) & 1u)) >> 16;
}

// ---------- rank-1 edge-encoder precompute ----------
__global__ void k_uc(const float* __restrict__ We_enc, const float* __restrict__ be_enc,
                     const float* __restrict__ We1, const float* __restrict__ We2,
                     float* __restrict__ uc) {
    int c = threadIdx.x;  // 0..127
    float u1 = 0.f, c1 = 0.f, u2 = 0.f, c2 = 0.f;
    for (int j = 0; j < 64; ++j) {
        float we = We_enc[j], be = be_enc[j];
        float w1 = We1[j * HC + c], w2 = We2[j * HC + c];
        u1 += we * w1; c1 += be * w1;
        u2 += we * w2; c2 += be * w2;
    }
    uc[c] = u1; uc[HC + c] = c1; uc[2 * HC + c] = u2; uc[3 * HC + c] = c2;
}

// ---------- pack layer-2 weights to bf16, B^T layout [n=512][k=128] ----------
__global__ __launch_bounds__(256) void k_wpack(
    const float* __restrict__ Wq, const float* __restrict__ Wk,
    const float* __restrict__ Wv, const float* __restrict__ Ws,
    unsigned short* __restrict__ Bph) {
    int t = blockIdx.x * 256 + threadIdx.x;   // 0..65535
    int nn = t >> 7;        // 0..511
    int kk = t & 127;
    int mat = nn >> 7, c = nn & 127;
    const float* W = (mat == 0) ? Wq : (mat == 1) ? Wk : (mat == 2) ? Wv : Ws;
    Bph[nn * 128 + kk] = (unsigned short)bf16_rne(W[kk * 128 + c]);
}

// ---------- CSR build (stable counting sort by dst) ----------
__global__ __launch_bounds__(256) void k_hist(const int* __restrict__ ei, int* __restrict__ deg, int E) {
    int t = blockIdx.x * blockDim.x + threadIdx.x;
    if (t < E) atomicAdd(&deg[ei[E + t]], 1);
}

// 3-pass hierarchical exclusive scan: deg[n] -> rowptr[n+1].
__global__ __launch_bounds__(256) void k_scan1(const int* __restrict__ deg, int* __restrict__ bsum, int n) {
    int t = blockIdx.x * 256 + threadIdx.x;
    int v = (t < n) ? deg[t] : 0;
#pragma unroll
    for (int off = 1; off < 64; off <<= 1) v += __shfl_xor(v, off);
    __shared__ int wsum[4];
    int lane = threadIdx.x & 63, w = threadIdx.x >> 6;
    if (lane == 0) wsum[w] = v;
    __syncthreads();
    if (threadIdx.x == 0) bsum[blockIdx.x] = wsum[0] + wsum[1] + wsum[2] + wsum[3];
}

__global__ __launch_bounds__(256) void k_scan2(int* __restrict__ bsum, int nb) {
    __shared__ int sh[256];
    int t = threadIdx.x;
    int v = (t < nb) ? bsum[t] : 0;
    sh[t] = v;
    __syncthreads();
    for (int off = 1; off < 256; off <<= 1) {
        int x = (t >= off) ? sh[t - off] : 0;
        __syncthreads();
        sh[t] += x;
        __syncthreads();
    }
    if (t < nb) bsum[t] = sh[t] - v;   // exclusive
}

__global__ __launch_bounds__(256) void k_scan3(const int* __restrict__ deg, const int* __restrict__ bsum,
                                               int* __restrict__ rowptr, int n, int E) {
    int t = blockIdx.x * 256 + threadIdx.x;
    int tid = threadIdx.x;
    int v = (t < n) ? deg[t] : 0;
    __shared__ int sh[256];
    sh[tid] = v;
    __syncthreads();
    for (int off = 1; off < 256; off <<= 1) {
        int x = (tid >= off) ? sh[tid - off] : 0;
        __syncthreads();
        sh[tid] += x;
        __syncthreads();
    }
    if (t < n) rowptr[t] = bsum[blockIdx.x] + sh[tid] - v;
    if (t == 0) rowptr[n] = E;
}

__global__ __launch_bounds__(256) void k_scatter(const int* __restrict__ ei, const int* __restrict__ rowptr,
                                                 int* __restrict__ cursor, int* __restrict__ eid, int E) {
    int t = blockIdx.x * blockDim.x + threadIdx.x;
    if (t >= E) return;
    int dst = ei[E + t];
    int pos = rowptr[dst] + atomicAdd(&cursor[dst], 1);
    eid[pos] = t;
}

__global__ __launch_bounds__(256) void k_bsort(const int* __restrict__ rowptr, int* __restrict__ eid, int n) {
    int t = blockIdx.x * blockDim.x + threadIdx.x;
    if (t >= n) return;
    int b = rowptr[t], e = rowptr[t + 1];
    for (int i = b + 1; i < e; ++i) {
        int key = eid[i];
        int j = i - 1;
        while (j >= b && eid[j] > key) { eid[j + 1] = eid[j]; --j; }
        eid[j + 1] = key;
    }
}

__global__ __launch_bounds__(256) void k_gather(const int* __restrict__ eid, const int* __restrict__ ei,
                                                const float* __restrict__ ea,
                                                int* __restrict__ srcs, float* __restrict__ eas, int E) {
    int t = blockIdx.x * blockDim.x + threadIdx.x;
    if (t >= E) return;
    int id = eid[t];
    srcs[t] = ei[id];
    eas[t] = ea[id];
}

// ---------- layer-1 node linears (K=6, vector ALU) ----------
// q,o stored f32; k,v stored packed bf16 into interleaved kv rows [256 ushort].
__global__ __launch_bounds__(256) void k_lin6(
    const float* __restrict__ X, int n,
    const float* __restrict__ Wq, const float* __restrict__ bq,
    const float* __restrict__ Wk, const float* __restrict__ bk,
    const float* __restrict__ Wv, const float* __restrict__ bv,
    const float* __restrict__ Ws, const float* __restrict__ bs,
    float* __restrict__ q, unsigned short* __restrict__ kv,
    float* __restrict__ o) {
    __shared__ float xs[16][6];
    const int base = blockIdx.x * 16;
    const int tid = threadIdx.x;
    for (int i = tid; i < 16 * 6; i += 256) {
        int ni = base + i / 6;
        xs[i / 6][i % 6] = (ni < n) ? X[(size_t)ni * 6 + (i % 6)] : 0.f;
    }
    __syncthreads();
    const int c = tid & 127;
    const int m = tid >> 7;  // 0 -> (q,k), 1 -> (v,o)
    const float* WA = m ? Wv : Wq;
    const float* WB = m ? Ws : Wk;
    float accA[16], accB[16];
#pragma unroll
    for (int i = 0; i < 16; ++i) { accA[i] = 0.f; accB[i] = 0.f; }
    for (int j = 0; j < 6; ++j) {
        float w0 = WA[j * HC + c];
        float w1 = WB[j * HC + c];
#pragma unroll
        for (int i = 0; i < 16; ++i) {
            float xv = xs[i][j];
            accA[i] += xv * w0;
            accB[i] += xv * w1;
        }
    }
    if (m == 0) {
        const float bA = bq[c], bB = bk[c];
#pragma unroll
        for (int i = 0; i < 16; ++i) {
            int ni = base + i;
            if (ni < n) {
                q[(size_t)ni * HC + c] = accA[i] + bA;
                kv[(size_t)ni * 256 + c] = (unsigned short)bf16_rne(accB[i] + bB);
            }
        }
    } else {
        const float bA = bv[c], bB = bs[c];
#pragma unroll
        for (int i = 0; i < 16; ++i) {
            int ni = base + i;
            if (ni < n) {
                kv[(size_t)ni * 256 + 128 + c] = (unsigned short)bf16_rne(accA[i] + bA);
                o[(size_t)ni * HC + c] = accB[i] + bB;
            }
        }
    }
}

// ---------- layer-2 node linears: split-A bf16 MFMA GEMM, LDS-staged bf16 B ----------
// Grid (ceil(n/128), 4). blockIdx.y = col quarter = matrix {q,k,v,s}.
__global__ __launch_bounds__(256, 4) void k_lin2(
    const unsigned short* __restrict__ hhi, const unsigned short* __restrict__ hlo,
    const unsigned short* __restrict__ Bph,
    const float* __restrict__ bq, const float* __restrict__ bk,
    const float* __restrict__ bv, const float* __restrict__ bs,
    float* __restrict__ q, unsigned short* __restrict__ kv,
    float* __restrict__ o, int n) {
    __shared__ unsigned short Bs[128][128];   // 32 KB
    const int tid = threadIdx.x;
    const int cq = blockIdx.y;                // matrix index
    for (int i = tid; i < 128 * 16; i += 256) {
        int kk8 = i & 15;
        int nnl = i >> 4;
        bf16x8 val = *(const bf16x8*)&Bph[((size_t)(cq * 128 + nnl)) * 128 + kk8 * 8];
        int swk = (kk8 ^ (nnl & 7)) * 8;
        *(bf16x8*)&Bs[nnl][swk] = val;
    }
    __syncthreads();

    const int wid = tid >> 6, l = tid & 63;
    const int la = l & 15, lk = l >> 4;
    const int mb = blockIdx.x * 128;
    int nodeA0 = mb + wid * 32 + la;
    int nodeA1 = nodeA0 + 16;
    if (nodeA0 >= n) nodeA0 = n - 1;
    if (nodeA1 >= n) nodeA1 = n - 1;
    const int sw = (la & 7) << 3;
    f32x4 acc0[8], acc1[8];
#pragma unroll
    for (int nt = 0; nt < 8; ++nt) {
        acc0[nt] = (f32x4){0.f, 0.f, 0.f, 0.f};
        acc1[nt] = (f32x4){0.f, 0.f, 0.f, 0.f};
    }
    // double-buffered A fragments (static indices via full unroll)
    bf16x8 a0h[2], a0l[2], a1h[2], a1l[2];
    {
        const int ko = lk * 8;
        a0h[0] = *(const bf16x8*)&hhi[(size_t)nodeA0 * 128 + ko];
        a0l[0] = *(const bf16x8*)&hlo[(size_t)nodeA0 * 128 + ko];
        a1h[0] = *(const bf16x8*)&hhi[(size_t)nodeA1 * 128 + ko];
        a1l[0] = *(const bf16x8*)&hlo[(size_t)nodeA1 * 128 + ko];
    }
#pragma unroll
    for (int ks = 0; ks < 4; ++ks) {
        const int cur = ks & 1, nxt = cur ^ 1;
        if (ks < 3) {
            const int ko = lk * 8 + (ks + 1) * 32;
            a0h[nxt] = *(const bf16x8*)&hhi[(size_t)nodeA0 * 128 + ko];
            a0l[nxt] = *(const bf16x8*)&hlo[(size_t)nodeA0 * 128 + ko];
            a1h[nxt] = *(const bf16x8*)&hhi[(size_t)nodeA1 * 128 + ko];
            a1l[nxt] = *(const bf16x8*)&hlo[(size_t)nodeA1 * 128 + ko];
        }
        const int rk = (lk * 8 + ks * 32) ^ sw;
#pragma unroll
        for (int nt = 0; nt < 8; ++nt) {
            bf16x8 Bh = *(const bf16x8*)&Bs[nt * 16 + la][rk];
            acc0[nt] = __builtin_amdgcn_mfma_f32_16x16x32_bf16(a0h[cur], Bh, acc0[nt], 0, 0, 0);
            acc0[nt] = __builtin_amdgcn_mfma_f32_16x16x32_bf16(a0l[cur], Bh, acc0[nt], 0, 0, 0);
            acc1[nt] = __builtin_amdgcn_mfma_f32_16x16x32_bf16(a1h[cur], Bh, acc1[nt], 0, 0, 0);
            acc1[nt] = __builtin_amdgcn_mfma_f32_16x16x32_bf16(a1l[cur], Bh, acc1[nt], 0, 0, 0);
        }
    }
    const float* bias = (cq == 0) ? bq : (cq == 1) ? bk : (cq == 2) ? bv : bs;
    const int crow0 = mb + wid * 32 + lk * 4;
#pragma unroll
    for (int nt = 0; nt < 8; ++nt) {
        const int col = nt * 16 + la;
        const float bb = bias[col];
        if (cq == 0 || cq == 3) {
            float* out = (cq == 0) ? q : o;
#pragma unroll
            for (int j = 0; j < 4; ++j) {
                int n0 = crow0 + j;
                if (n0 < n) out[(size_t)n0 * 128 + col] = acc0[nt][j] + bb;
                int n1 = n0 + 16;
                if (n1 < n) out[(size_t)n1 * 128 + col] = acc1[nt][j] + bb;
            }
        } else {
            const int co = (cq == 1) ? col : 128 + col;
#pragma unroll
            for (int j = 0; j < 4; ++j) {
                int n0 = crow0 + j;
                if (n0 < n) kv[(size_t)n0 * 256 + co] = (unsigned short)bf16_rne(acc0[nt][j] + bb);
                int n1 = n0 + 16;
                if (n1 < n) kv[(size_t)n1 * 256 + co] = (unsigned short)bf16_rne(acc1[nt][j] + bb);
            }
        }
    }
}

// ---------- fused online-softmax attention, one wave per dst node ----------
// Lane l holds channels {2l, 2l+1}; lanes 0..31 = head0, 32..63 = head1.
template <int MODE>
__global__ __launch_bounds__(256) void k_attn(
    const float* __restrict__ q, const unsigned int* __restrict__ kvp,
    const int* __restrict__ rowptr, const int* __restrict__ srcs, const float* __restrict__ eas,
    const float* __restrict__ ucu, const float* __restrict__ ucc,
    float* __restrict__ io, unsigned short* __restrict__ hhi, unsigned short* __restrict__ hlo,
    int n) {
    int wid = (int)((blockIdx.x * (size_t)blockDim.x + threadIdx.x) >> 6);
    int lane = threadIdx.x & 63;
    if (wid >= n) return;
    const float2* q2 = (const float2*)q;
    float2 qr = q2[(size_t)wid * 64 + lane];
    float2 uu = ((const float2*)ucu)[lane];
    float2 cc = ((const float2*)ucc)[lane];
    int b = rowptr[wid], e = rowptr[wid + 1];
    float m = -INFINITY, s = 0.f;
    float ax = 0.f, ay = 0.f;
    if (b < e) {
        int src = srcs[b];
        float eav = eas[b];
        unsigned ku = kvp[(size_t)src * 128 + lane];
        unsigned vu = kvp[(size_t)src * 128 + 64 + lane];
        for (int p = b; p < e; ++p) {
            // prefetch next edge (clamped; redundant load on last iter)
            int pn = (p + 1 < e) ? p + 1 : p;
            int srcn = srcs[pn];
            float eavn = eas[pn];
            unsigned kun = kvp[(size_t)srcn * 128 + lane];
            unsigned vun = kvp[(size_t)srcn * 128 + 64 + lane];

            float krx = __uint_as_float(ku << 16);
            float kry = __uint_as_float(ku & 0xffff0000u);
            float vrx = __uint_as_float(vu << 16);
            float vry = __uint_as_float(vu & 0xffff0000u);
            float eh0 = eav * uu.x + cc.x;
            float eh1 = eav * uu.y + cc.y;
            float d = qr.x * (krx + eh0) + qr.y * (kry + eh1);
            d += __shfl_xor(d, 1); d += __shfl_xor(d, 2); d += __shfl_xor(d, 4);
            d += __shfl_xor(d, 8); d += __shfl_xor(d, 16);   // per-head sum
            float a = d * 0.125f;                            // / sqrt(64)
            float nm = fmaxf(m, a);
            float sc = __expf(m - nm);
            float pw = __expf(a - nm);
            s = s * sc + pw;
            ax = ax * sc + pw * (vrx + eh0);
            ay = ay * sc + pw * (vry + eh1);
            m = nm;
            ku = kun; vu = vun; eav = eavn;
        }
    }
    float inv = 1.f / (s + 1e-16f);
    float2 skip = ((const float2*)io)[(size_t)wid * 64 + lane];
    float o0 = ax * inv + skip.x;
    float o1 = ay * inv + skip.y;
    if (MODE == 1) {
        o0 = fmaxf(o0, 0.f); o1 = fmaxf(o1, 0.f);
        unsigned h0 = bf16_rne(o0);
        unsigned h1 = bf16_rne(o1);
        float r0 = o0 - __uint_as_float(h0 << 16);
        float r1 = o1 - __uint_as_float(h1 << 16);
        unsigned l0 = bf16_rne(r0);
        unsigned l1 = bf16_rne(r1);
        ushort2* ph = (ushort2*)&hhi[(size_t)wid * 128 + 2 * lane];
        ushort2* pl = (ushort2*)&hlo[(size_t)wid * 128 + 2 * lane];
        *ph = make_ushort2((unsigned short)h0, (unsigned short)h1);
        *pl = make_ushort2((unsigned short)l0, (unsigned short)l1);
    } else {
        ((float2*)io)[(size_t)wid * 64 + lane] = make_float2(o0, o1);
    }
}

// ---------- fc head (relu fused), one wave per node ----------
__global__ __launch_bounds__(256) void k_fc(
    const float* __restrict__ h, const float* __restrict__ Wfc,
    const float* __restrict__ bfc, float* __restrict__ out, int n) {
    int w = (int)((blockIdx.x * (size_t)blockDim.x + threadIdx.x) >> 6);
    int lane = threadIdx.x & 63;
    if (w >= n) return;
    const float2* h2 = (const float2*)h;
    const float2* w2 = (const float2*)Wfc;
    float2 hv = h2[(size_t)w * 64 + lane];
    float2 wv = w2[lane];
    float vsum = fmaxf(hv.x, 0.f) * wv.x + fmaxf(hv.y, 0.f) * wv.y;
#pragma unroll
    for (int off = 1; off < 64; off <<= 1) vsum += __shfl_xor(vsum, off);
    if (lane == 0) out[w] = vsum + bfc[0];
}

extern "C" void kernel_launch(void* const* d_in, const int* in_sizes, int n_in,
                              void* d_out, int out_size, void* d_ws, size_t ws_size,
                              hipStream_t stream) {
    const float* x      = (const float*)d_in[0];
    const int*   ei     = (const int*)d_in[1];
    const float* ea     = (const float*)d_in[2];
    const float* We_enc = (const float*)d_in[3];
    const float* be_enc = (const float*)d_in[4];
    const float* Wq1 = (const float*)d_in[5],  *bq1 = (const float*)d_in[6];
    const float* Wk1 = (const float*)d_in[7],  *bk1 = (const float*)d_in[8];
    const float* Wv1 = (const float*)d_in[9],  *bv1 = (const float*)d_in[10];
    const float* We1 = (const float*)d_in[11];
    const float* Ws1 = (const float*)d_in[12], *bs1 = (const float*)d_in[13];
    const float* Wq2 = (const float*)d_in[14], *bq2 = (const float*)d_in[15];
    const float* Wk2 = (const float*)d_in[16], *bk2 = (const float*)d_in[17];
    const float* Wv2 = (const float*)d_in[18], *bv2 = (const float*)d_in[19];
    const float* We2 = (const float*)d_in[20];
    const float* Ws2 = (const float*)d_in[21], *bs2 = (const float*)d_in[22];
    const float* Wfc = (const float*)d_in[23], *bfc = (const float*)d_in[24];

    const int n = in_sizes[0] / 6;   // 50000
    const int E = in_sizes[2];       // 409600

    float* ws = (float*)d_ws;
    size_t off = 0;
    float* qb = ws + off; off += (size_t)n * HC;
    float* Bb = ws + off; off += (size_t)n * HC;   // skip-init / h buffer
    unsigned short* kv16 = (unsigned short*)(ws + off); off += (size_t)n * HC;  // interleaved k|v bf16
    int* rowptr = (int*)(ws + off); off += (size_t)(n + 1);
    int* deg    = (int*)(ws + off); off += (size_t)n;   // also scatter cursor
    int* bsum   = (int*)(ws + off); off += 256;
    int* eid    = (int*)(ws + off); off += (size_t)E;
    int* srcs   = (int*)(ws + off); off += (size_t)E;
    float* eas  = ws + off; off += (size_t)E;
    float* uc   = ws + off; off += 512;
    unsigned short* hhi = (unsigned short*)(ws + off); off += (size_t)n * HC / 2;
    unsigned short* hlo = (unsigned short*)(ws + off); off += (size_t)n * HC / 2;
    unsigned short* Bph = (unsigned short*)(ws + off); off += 512 * 128 / 2;

    const int eb = (E + 255) / 256;
    const int nb = (n + 255) / 256;
    const int wb = (int)(((size_t)n * 64 + 255) / 256);

    hipLaunchKernelGGL(k_uc, dim3(1), dim3(128), 0, stream, We_enc, be_enc, We1, We2, uc);
    hipLaunchKernelGGL(k_wpack, dim3(256), dim3(256), 0, stream, Wq2, Wk2, Wv2, Ws2, Bph);

    // ---- CSR build (shared by both layers) ----
    hipMemsetAsync(deg, 0, (size_t)n * sizeof(int), stream);
    hipLaunchKernelGGL(k_hist, dim3(eb), dim3(256), 0, stream, ei, deg, E);
    hipLaunchKernelGGL(k_scan1, dim3(nb), dim3(256), 0, stream, deg, bsum, n);
    hipLaunchKernelGGL(k_scan2, dim3(1), dim3(256), 0, stream, bsum, nb);
    hipLaunchKernelGGL(k_scan3, dim3(nb), dim3(256), 0, stream, deg, bsum, rowptr, n, E);
    hipMemsetAsync(deg, 0, (size_t)n * sizeof(int), stream);  // reuse as cursor
    hipLaunchKernelGGL(k_scatter, dim3(eb), dim3(256), 0, stream, ei, rowptr, deg, eid, E);
    hipLaunchKernelGGL(k_bsort, dim3(nb), dim3(256), 0, stream, rowptr, eid, n);
    hipLaunchKernelGGL(k_gather, dim3(eb), dim3(256), 0, stream, eid, ei, ea, srcs, eas, E);

    // ---- layer 1 ----
    hipLaunchKernelGGL(k_lin6, dim3((n + 15) / 16), dim3(256), 0, stream,
                       x, n, Wq1, bq1, Wk1, bk1, Wv1, bv1, Ws1, bs1, qb, kv16, Bb);
    hipLaunchKernelGGL((k_attn<1>), dim3(wb), dim3(256), 0, stream,
                       qb, (const unsigned int*)kv16,
                       rowptr, srcs, eas, uc, uc + HC, Bb, hhi, hlo, n);

    // ---- layer 2 (MFMA GEMM reads hhi/hlo; writes q f32, k/v bf16, skip into Bb) ----
    hipLaunchKernelGGL(k_lin2, dim3((n + 127) / 128, 4), dim3(256), 0, stream,
                       hhi, hlo, Bph, bq2, bk2, bv2, bs2, qb, kv16, Bb, n);
    hipLaunchKernelGGL((k_attn<0>), dim3(wb), dim3(256), 0, stream,
                       qb, (const unsigned int*)kv16,
                       rowptr, srcs, eas, uc + 2 * HC, uc + 3 * HC, Bb,
                       (unsigned short*)nullptr, (unsigned short*)nullptr, n);

    // ---- fc head ----
    hipLaunchKernelGGL(k_fc, dim3(wb), dim3(256), 0, stream, Bb, Wfc, bfc, (float*)d_out, n);
}

// Round 9
// 274.794 us; speedup vs baseline: 1.7719x; 1.0715x over previous
//
#include <hip/hip_runtime.h>

// TemporalGNN: 2x TransformerConv(H=2, C=64) + edge encoder + fc head.
// Edge encoder is rank-1 (edge_attr is [E,1]): eh_l = ea[e]*u_l + c_l.
// Edge phase: stable counting-sort by dst, then one wave per dst node does
// online-softmax attention. R9: 2-wide edge pipeline -- two independent
// online-softmax accumulator sets (merged at the end) + 4 gather loads in
// flight; R8 profile showed k_attn latency-bound (VALU 44%, HBM 27%).
// Layer-2 linears: MFMA GEMM, split-bf16 A x bf16 B, 32 KB LDS B panel.

#define HC 128   // H*C

typedef __attribute__((ext_vector_type(8))) short bf16x8;
typedef __attribute__((ext_vector_type(4))) float f32x4;

__device__ __forceinline__ unsigned bf16_rne(float f) {
    unsigned u = __float_as_uint(f);
    return (u + 0x7fffu + ((u >> 16) & 1u)) >> 16;
}

// ---------- rank-1 edge-encoder precompute ----------
__global__ void k_uc(const float* __restrict__ We_enc, const float* __restrict__ be_enc,
                     const float* __restrict__ We1, const float* __restrict__ We2,
                     float* __restrict__ uc) {
    int c = threadIdx.x;  // 0..127
    float u1 = 0.f, c1 = 0.f, u2 = 0.f, c2 = 0.f;
    for (int j = 0; j < 64; ++j) {
        float we = We_enc[j], be = be_enc[j];
        float w1 = We1[j * HC + c], w2 = We2[j * HC + c];
        u1 += we * w1; c1 += be * w1;
        u2 += we * w2; c2 += be * w2;
    }
    uc[c] = u1; uc[HC + c] = c1; uc[2 * HC + c] = u2; uc[3 * HC + c] = c2;
}

// ---------- pack layer-2 weights to bf16, B^T layout [n=512][k=128] ----------
__global__ __launch_bounds__(256) void k_wpack(
    const float* __restrict__ Wq, const float* __restrict__ Wk,
    const float* __restrict__ Wv, const float* __restrict__ Ws,
    unsigned short* __restrict__ Bph) {
    int t = blockIdx.x * 256 + threadIdx.x;   // 0..65535
    int nn = t >> 7;        // 0..511
    int kk = t & 127;
    int mat = nn >> 7, c = nn & 127;
    const float* W = (mat == 0) ? Wq : (mat == 1) ? Wk : (mat == 2) ? Wv : Ws;
    Bph[nn * 128 + kk] = (unsigned short)bf16_rne(W[kk * 128 + c]);
}

// ---------- CSR build (stable counting sort by dst) ----------
__global__ __launch_bounds__(256) void k_hist(const int* __restrict__ ei, int* __restrict__ deg, int E) {
    int t = blockIdx.x * blockDim.x + threadIdx.x;
    if (t < E) atomicAdd(&deg[ei[E + t]], 1);
}

// 3-pass hierarchical exclusive scan: deg[n] -> rowptr[n+1].
__global__ __launch_bounds__(256) void k_scan1(const int* __restrict__ deg, int* __restrict__ bsum, int n) {
    int t = blockIdx.x * 256 + threadIdx.x;
    int v = (t < n) ? deg[t] : 0;
#pragma unroll
    for (int off = 1; off < 64; off <<= 1) v += __shfl_xor(v, off);
    __shared__ int wsum[4];
    int lane = threadIdx.x & 63, w = threadIdx.x >> 6;
    if (lane == 0) wsum[w] = v;
    __syncthreads();
    if (threadIdx.x == 0) bsum[blockIdx.x] = wsum[0] + wsum[1] + wsum[2] + wsum[3];
}

__global__ __launch_bounds__(256) void k_scan2(int* __restrict__ bsum, int nb) {
    __shared__ int sh[256];
    int t = threadIdx.x;
    int v = (t < nb) ? bsum[t] : 0;
    sh[t] = v;
    __syncthreads();
    for (int off = 1; off < 256; off <<= 1) {
        int x = (t >= off) ? sh[t - off] : 0;
        __syncthreads();
        sh[t] += x;
        __syncthreads();
    }
    if (t < nb) bsum[t] = sh[t] - v;   // exclusive
}

__global__ __launch_bounds__(256) void k_scan3(const int* __restrict__ deg, const int* __restrict__ bsum,
                                               int* __restrict__ rowptr, int n, int E) {
    int t = blockIdx.x * 256 + threadIdx.x;
    int tid = threadIdx.x;
    int v = (t < n) ? deg[t] : 0;
    __shared__ int sh[256];
    sh[tid] = v;
    __syncthreads();
    for (int off = 1; off < 256; off <<= 1) {
        int x = (tid >= off) ? sh[tid - off] : 0;
        __syncthreads();
        sh[tid] += x;
        __syncthreads();
    }
    if (t < n) rowptr[t] = bsum[blockIdx.x] + sh[tid] - v;
    if (t == 0) rowptr[n] = E;
}

__global__ __launch_bounds__(256) void k_scatter(const int* __restrict__ ei, const int* __restrict__ rowptr,
                                                 int* __restrict__ cursor, int* __restrict__ eid, int E) {
    int t = blockIdx.x * blockDim.x + threadIdx.x;
    if (t >= E) return;
    int dst = ei[E + t];
    int pos = rowptr[dst] + atomicAdd(&cursor[dst], 1);
    eid[pos] = t;
}

__global__ __launch_bounds__(256) void k_bsort(const int* __restrict__ rowptr, int* __restrict__ eid, int n) {
    int t = blockIdx.x * blockDim.x + threadIdx.x;
    if (t >= n) return;
    int b = rowptr[t], e = rowptr[t + 1];
    for (int i = b + 1; i < e; ++i) {
        int key = eid[i];
        int j = i - 1;
        while (j >= b && eid[j] > key) { eid[j + 1] = eid[j]; --j; }
        eid[j + 1] = key;
    }
}

__global__ __launch_bounds__(256) void k_gather(const int* __restrict__ eid, const int* __restrict__ ei,
                                                const float* __restrict__ ea,
                                                int* __restrict__ srcs, float* __restrict__ eas, int E) {
    int t = blockIdx.x * blockDim.x + threadIdx.x;
    if (t >= E) return;
    int id = eid[t];
    srcs[t] = ei[id];
    eas[t] = ea[id];
}

// ---------- layer-1 node linears (K=6, vector ALU) ----------
// q,o stored f32; k,v stored packed bf16 into interleaved kv rows [256 ushort].
__global__ __launch_bounds__(256) void k_lin6(
    const float* __restrict__ X, int n,
    const float* __restrict__ Wq, const float* __restrict__ bq,
    const float* __restrict__ Wk, const float* __restrict__ bk,
    const float* __restrict__ Wv, const float* __restrict__ bv,
    const float* __restrict__ Ws, const float* __restrict__ bs,
    float* __restrict__ q, unsigned short* __restrict__ kv,
    float* __restrict__ o) {
    __shared__ float xs[16][6];
    const int base = blockIdx.x * 16;
    const int tid = threadIdx.x;
    for (int i = tid; i < 16 * 6; i += 256) {
        int ni = base + i / 6;
        xs[i / 6][i % 6] = (ni < n) ? X[(size_t)ni * 6 + (i % 6)] : 0.f;
    }
    __syncthreads();
    const int c = tid & 127;
    const int m = tid >> 7;  // 0 -> (q,k), 1 -> (v,o)
    const float* WA = m ? Wv : Wq;
    const float* WB = m ? Ws : Wk;
    float accA[16], accB[16];
#pragma unroll
    for (int i = 0; i < 16; ++i) { accA[i] = 0.f; accB[i] = 0.f; }
    for (int j = 0; j < 6; ++j) {
        float w0 = WA[j * HC + c];
        float w1 = WB[j * HC + c];
#pragma unroll
        for (int i = 0; i < 16; ++i) {
            float xv = xs[i][j];
            accA[i] += xv * w0;
            accB[i] += xv * w1;
        }
    }
    if (m == 0) {
        const float bA = bq[c], bB = bk[c];
#pragma unroll
        for (int i = 0; i < 16; ++i) {
            int ni = base + i;
            if (ni < n) {
                q[(size_t)ni * HC + c] = accA[i] + bA;
                kv[(size_t)ni * 256 + c] = (unsigned short)bf16_rne(accB[i] + bB);
            }
        }
    } else {
        const float bA = bv[c], bB = bs[c];
#pragma unroll
        for (int i = 0; i < 16; ++i) {
            int ni = base + i;
            if (ni < n) {
                kv[(size_t)ni * 256 + 128 + c] = (unsigned short)bf16_rne(accA[i] + bA);
                o[(size_t)ni * HC + c] = accB[i] + bB;
            }
        }
    }
}

// ---------- layer-2 node linears: split-A bf16 MFMA GEMM, LDS-staged bf16 B ----------
// Grid (ceil(n/128), 4). blockIdx.y = col quarter = matrix {q,k,v,s}.
__global__ __launch_bounds__(256, 4) void k_lin2(
    const unsigned short* __restrict__ hhi, const unsigned short* __restrict__ hlo,
    const unsigned short* __restrict__ Bph,
    const float* __restrict__ bq, const float* __restrict__ bk,
    const float* __restrict__ bv, const float* __restrict__ bs,
    float* __restrict__ q, unsigned short* __restrict__ kv,
    float* __restrict__ o, int n) {
    __shared__ unsigned short Bs[128][128];   // 32 KB
    const int tid = threadIdx.x;
    const int cq = blockIdx.y;                // matrix index
    for (int i = tid; i < 128 * 16; i += 256) {
        int kk8 = i & 15;
        int nnl = i >> 4;
        bf16x8 val = *(const bf16x8*)&Bph[((size_t)(cq * 128 + nnl)) * 128 + kk8 * 8];
        int swk = (kk8 ^ (nnl & 7)) * 8;
        *(bf16x8*)&Bs[nnl][swk] = val;
    }
    __syncthreads();

    const int wid = tid >> 6, l = tid & 63;
    const int la = l & 15, lk = l >> 4;
    const int mb = blockIdx.x * 128;
    int nodeA0 = mb + wid * 32 + la;
    int nodeA1 = nodeA0 + 16;
    if (nodeA0 >= n) nodeA0 = n - 1;
    if (nodeA1 >= n) nodeA1 = n - 1;
    const int sw = (la & 7) << 3;
    f32x4 acc0[8], acc1[8];
#pragma unroll
    for (int nt = 0; nt < 8; ++nt) {
        acc0[nt] = (f32x4){0.f, 0.f, 0.f, 0.f};
        acc1[nt] = (f32x4){0.f, 0.f, 0.f, 0.f};
    }
    // double-buffered A fragments (static indices via full unroll)
    bf16x8 a0h[2], a0l[2], a1h[2], a1l[2];
    {
        const int ko = lk * 8;
        a0h[0] = *(const bf16x8*)&hhi[(size_t)nodeA0 * 128 + ko];
        a0l[0] = *(const bf16x8*)&hlo[(size_t)nodeA0 * 128 + ko];
        a1h[0] = *(const bf16x8*)&hhi[(size_t)nodeA1 * 128 + ko];
        a1l[0] = *(const bf16x8*)&hlo[(size_t)nodeA1 * 128 + ko];
    }
#pragma unroll
    for (int ks = 0; ks < 4; ++ks) {
        const int cur = ks & 1, nxt = cur ^ 1;
        if (ks < 3) {
            const int ko = lk * 8 + (ks + 1) * 32;
            a0h[nxt] = *(const bf16x8*)&hhi[(size_t)nodeA0 * 128 + ko];
            a0l[nxt] = *(const bf16x8*)&hlo[(size_t)nodeA0 * 128 + ko];
            a1h[nxt] = *(const bf16x8*)&hhi[(size_t)nodeA1 * 128 + ko];
            a1l[nxt] = *(const bf16x8*)&hlo[(size_t)nodeA1 * 128 + ko];
        }
        const int rk = (lk * 8 + ks * 32) ^ sw;
#pragma unroll
        for (int nt = 0; nt < 8; ++nt) {
            bf16x8 Bh = *(const bf16x8*)&Bs[nt * 16 + la][rk];
            acc0[nt] = __builtin_amdgcn_mfma_f32_16x16x32_bf16(a0h[cur], Bh, acc0[nt], 0, 0, 0);
            acc0[nt] = __builtin_amdgcn_mfma_f32_16x16x32_bf16(a0l[cur], Bh, acc0[nt], 0, 0, 0);
            acc1[nt] = __builtin_amdgcn_mfma_f32_16x16x32_bf16(a1h[cur], Bh, acc1[nt], 0, 0, 0);
            acc1[nt] = __builtin_amdgcn_mfma_f32_16x16x32_bf16(a1l[cur], Bh, acc1[nt], 0, 0, 0);
        }
    }
    const float* bias = (cq == 0) ? bq : (cq == 1) ? bk : (cq == 2) ? bv : bs;
    const int crow0 = mb + wid * 32 + lk * 4;
#pragma unroll
    for (int nt = 0; nt < 8; ++nt) {
        const int col = nt * 16 + la;
        const float bb = bias[col];
        if (cq == 0 || cq == 3) {
            float* out = (cq == 0) ? q : o;
#pragma unroll
            for (int j = 0; j < 4; ++j) {
                int n0 = crow0 + j;
                if (n0 < n) out[(size_t)n0 * 128 + col] = acc0[nt][j] + bb;
                int n1 = n0 + 16;
                if (n1 < n) out[(size_t)n1 * 128 + col] = acc1[nt][j] + bb;
            }
        } else {
            const int co = (cq == 1) ? col : 128 + col;
#pragma unroll
            for (int j = 0; j < 4; ++j) {
                int n0 = crow0 + j;
                if (n0 < n) kv[(size_t)n0 * 256 + co] = (unsigned short)bf16_rne(acc0[nt][j] + bb);
                int n1 = n0 + 16;
                if (n1 < n) kv[(size_t)n1 * 256 + co] = (unsigned short)bf16_rne(acc1[nt][j] + bb);
            }
        }
    }
}

// ---------- fused online-softmax attention, one wave per dst node ----------
// Lane l holds channels {2l, 2l+1}; lanes 0..31 = head0, 32..63 = head1.
// 2-wide edge pipeline: even/odd edges feed independent accumulator sets
// (merged at the end); 4 gather loads in flight per wave.
#define ATTN_UPD(mX, sX, axX, ayX, ku, vu, eav)                         \
    do {                                                                \
        float krx = __uint_as_float((ku) << 16);                        \
        float kry = __uint_as_float((ku) & 0xffff0000u);                \
        float vrx = __uint_as_float((vu) << 16);                        \
        float vry = __uint_as_float((vu) & 0xffff0000u);                \
        float eh0 = (eav) * uu.x + cc.x;                                \
        float eh1 = (eav) * uu.y + cc.y;                                \
        float d = qr.x * (krx + eh0) + qr.y * (kry + eh1);              \
        d += __shfl_xor(d, 1); d += __shfl_xor(d, 2);                   \
        d += __shfl_xor(d, 4); d += __shfl_xor(d, 8);                   \
        d += __shfl_xor(d, 16);                                         \
        float a = d * 0.125f;                                           \
        float nm2 = fmaxf(mX, a);                                       \
        float sc = __expf(mX - nm2);                                    \
        float pw = __expf(a - nm2);                                     \
        sX = sX * sc + pw;                                              \
        axX = axX * sc + pw * (vrx + eh0);                              \
        ayX = ayX * sc + pw * (vry + eh1);                              \
        mX = nm2;                                                       \
    } while (0)

template <int MODE>
__global__ __launch_bounds__(256) void k_attn(
    const float* __restrict__ q, const unsigned int* __restrict__ kvp,
    const int* __restrict__ rowptr, const int* __restrict__ srcs, const float* __restrict__ eas,
    const float* __restrict__ ucu, const float* __restrict__ ucc,
    float* __restrict__ io, unsigned short* __restrict__ hhi, unsigned short* __restrict__ hlo,
    int n) {
    int wid = (int)((blockIdx.x * (size_t)blockDim.x + threadIdx.x) >> 6);
    int lane = threadIdx.x & 63;
    if (wid >= n) return;
    const float2* q2 = (const float2*)q;
    float2 qr = q2[(size_t)wid * 64 + lane];
    float2 uu = ((const float2*)ucu)[lane];
    float2 cc = ((const float2*)ucc)[lane];
    int b = rowptr[wid], e = rowptr[wid + 1];
    float mA = -INFINITY, sA = 0.f, axA = 0.f, ayA = 0.f;
    float mB = -INFINITY, sB = 0.f, axB = 0.f, ayB = 0.f;
    if (b < e) {
        int p1i = (b + 1 < e) ? b + 1 : b;
        int s0 = srcs[b], s1 = srcs[p1i];
        float ea0 = eas[b], ea1 = eas[p1i];
        unsigned ku0 = kvp[(size_t)s0 * 128 + lane];
        unsigned vu0 = kvp[(size_t)s0 * 128 + 64 + lane];
        unsigned ku1 = kvp[(size_t)s1 * 128 + lane];
        unsigned vu1 = kvp[(size_t)s1 * 128 + 64 + lane];
        int p = b;
        for (; p + 1 < e; p += 2) {
            // prefetch pair (p+2, p+3), clamped
            int pn0 = (p + 2 < e) ? p + 2 : e - 1;
            int pn1 = (p + 3 < e) ? p + 3 : e - 1;
            int sn0 = srcs[pn0], sn1 = srcs[pn1];
            float ean0 = eas[pn0], ean1 = eas[pn1];
            unsigned kun0 = kvp[(size_t)sn0 * 128 + lane];
            unsigned vun0 = kvp[(size_t)sn0 * 128 + 64 + lane];
            unsigned kun1 = kvp[(size_t)sn1 * 128 + lane];
            unsigned vun1 = kvp[(size_t)sn1 * 128 + 64 + lane];
            // two independent online-softmax updates
            ATTN_UPD(mA, sA, axA, ayA, ku0, vu0, ea0);
            ATTN_UPD(mB, sB, axB, ayB, ku1, vu1, ea1);
            ku0 = kun0; vu0 = vun0; ea0 = ean0;
            ku1 = kun1; vu1 = vun1; ea1 = ean1;
        }
        if (p < e) {   // odd tail -> accumulator A
            ATTN_UPD(mA, sA, axA, ayA, ku0, vu0, ea0);
        }
    }
    // merge B into A (A owns >=1 edge whenever b<e; scB==0 if B unused)
    float s, ax, ay;
    if (b < e) {
        float nm = fmaxf(mA, mB);
        float scA = __expf(mA - nm);
        float scB = __expf(mB - nm);
        s = sA * scA + sB * scB;
        ax = axA * scA + axB * scB;
        ay = ayA * scA + ayB * scB;
    } else {
        s = 0.f; ax = 0.f; ay = 0.f;
    }
    float inv = 1.f / (s + 1e-16f);
    float2 skip = ((const float2*)io)[(size_t)wid * 64 + lane];
    float o0 = ax * inv + skip.x;
    float o1 = ay * inv + skip.y;
    if (MODE == 1) {
        o0 = fmaxf(o0, 0.f); o1 = fmaxf(o1, 0.f);
        unsigned h0 = bf16_rne(o0);
        unsigned h1 = bf16_rne(o1);
        float r0 = o0 - __uint_as_float(h0 << 16);
        float r1 = o1 - __uint_as_float(h1 << 16);
        unsigned l0 = bf16_rne(r0);
        unsigned l1 = bf16_rne(r1);
        ushort2* ph = (ushort2*)&hhi[(size_t)wid * 128 + 2 * lane];
        ushort2* pl = (ushort2*)&hlo[(size_t)wid * 128 + 2 * lane];
        *ph = make_ushort2((unsigned short)h0, (unsigned short)h1);
        *pl = make_ushort2((unsigned short)l0, (unsigned short)l1);
    } else {
        ((float2*)io)[(size_t)wid * 64 + lane] = make_float2(o0, o1);
    }
}

// ---------- fc head (relu fused), one wave per node ----------
__global__ __launch_bounds__(256) void k_fc(
    const float* __restrict__ h, const float* __restrict__ Wfc,
    const float* __restrict__ bfc, float* __restrict__ out, int n) {
    int w = (int)((blockIdx.x * (size_t)blockDim.x + threadIdx.x) >> 6);
    int lane = threadIdx.x & 63;
    if (w >= n) return;
    const float2* h2 = (const float2*)h;
    const float2* w2 = (const float2*)Wfc;
    float2 hv = h2[(size_t)w * 64 + lane];
    float2 wv = w2[lane];
    float vsum = fmaxf(hv.x, 0.f) * wv.x + fmaxf(hv.y, 0.f) * wv.y;
#pragma unroll
    for (int off = 1; off < 64; off <<= 1) vsum += __shfl_xor(vsum, off);
    if (lane == 0) out[w] = vsum + bfc[0];
}

extern "C" void kernel_launch(void* const* d_in, const int* in_sizes, int n_in,
                              void* d_out, int out_size, void* d_ws, size_t ws_size,
                              hipStream_t stream) {
    const float* x      = (const float*)d_in[0];
    const int*   ei     = (const int*)d_in[1];
    const float* ea     = (const float*)d_in[2];
    const float* We_enc = (const float*)d_in[3];
    const float* be_enc = (const float*)d_in[4];
    const float* Wq1 = (const float*)d_in[5],  *bq1 = (const float*)d_in[6];
    const float* Wk1 = (const float*)d_in[7],  *bk1 = (const float*)d_in[8];
    const float* Wv1 = (const float*)d_in[9],  *bv1 = (const float*)d_in[10];
    const float* We1 = (const float*)d_in[11];
    const float* Ws1 = (const float*)d_in[12], *bs1 = (const float*)d_in[13];
    const float* Wq2 = (const float*)d_in[14], *bq2 = (const float*)d_in[15];
    const float* Wk2 = (const float*)d_in[16], *bk2 = (const float*)d_in[17];
    const float* Wv2 = (const float*)d_in[18], *bv2 = (const float*)d_in[19];
    const float* We2 = (const float*)d_in[20];
    const float* Ws2 = (const float*)d_in[21], *bs2 = (const float*)d_in[22];
    const float* Wfc = (const float*)d_in[23], *bfc = (const float*)d_in[24];

    const int n = in_sizes[0] / 6;   // 50000
    const int E = in_sizes[2];       // 409600

    float* ws = (float*)d_ws;
    size_t off = 0;
    float* qb = ws + off; off += (size_t)n * HC;
    float* Bb = ws + off; off += (size_t)n * HC;   // skip-init / h buffer
    unsigned short* kv16 = (unsigned short*)(ws + off); off += (size_t)n * HC;  // interleaved k|v bf16
    int* rowptr = (int*)(ws + off); off += (size_t)(n + 1);
    int* deg    = (int*)(ws + off); off += (size_t)n;   // also scatter cursor
    int* bsum   = (int*)(ws + off); off += 256;
    int* eid    = (int*)(ws + off); off += (size_t)E;
    int* srcs   = (int*)(ws + off); off += (size_t)E;
    float* eas  = ws + off; off += (size_t)E;
    float* uc   = ws + off; off += 512;
    unsigned short* hhi = (unsigned short*)(ws + off); off += (size_t)n * HC / 2;
    unsigned short* hlo = (unsigned short*)(ws + off); off += (size_t)n * HC / 2;
    unsigned short* Bph = (unsigned short*)(ws + off); off += 512 * 128 / 2;

    const int eb = (E + 255) / 256;
    const int nb = (n + 255) / 256;
    const int wb = (int)(((size_t)n * 64 + 255) / 256);

    hipLaunchKernelGGL(k_uc, dim3(1), dim3(128), 0, stream, We_enc, be_enc, We1, We2, uc);
    hipLaunchKernelGGL(k_wpack, dim3(256), dim3(256), 0, stream, Wq2, Wk2, Wv2, Ws2, Bph);

    // ---- CSR build (shared by both layers) ----
    hipMemsetAsync(deg, 0, (size_t)n * sizeof(int), stream);
    hipLaunchKernelGGL(k_hist, dim3(eb), dim3(256), 0, stream, ei, deg, E);
    hipLaunchKernelGGL(k_scan1, dim3(nb), dim3(256), 0, stream, deg, bsum, n);
    hipLaunchKernelGGL(k_scan2, dim3(1), dim3(256), 0, stream, bsum, nb);
    hipLaunchKernelGGL(k_scan3, dim3(nb), dim3(256), 0, stream, deg, bsum, rowptr, n, E);
    hipMemsetAsync(deg, 0, (size_t)n * sizeof(int), stream);  // reuse as cursor
    hipLaunchKernelGGL(k_scatter, dim3(eb), dim3(256), 0, stream, ei, rowptr, deg, eid, E);
    hipLaunchKernelGGL(k_bsort, dim3(nb), dim3(256), 0, stream, rowptr, eid, n);
    hipLaunchKernelGGL(k_gather, dim3(eb), dim3(256), 0, stream, eid, ei, ea, srcs, eas, E);

    // ---- layer 1 ----
    hipLaunchKernelGGL(k_lin6, dim3((n + 15) / 16), dim3(256), 0, stream,
                       x, n, Wq1, bq1, Wk1, bk1, Wv1, bv1, Ws1, bs1, qb, kv16, Bb);
    hipLaunchKernelGGL((k_attn<1>), dim3(wb), dim3(256), 0, stream,
                       qb, (const unsigned int*)kv16,
                       rowptr, srcs, eas, uc, uc + HC, Bb, hhi, hlo, n);

    // ---- layer 2 (MFMA GEMM reads hhi/hlo; writes q f32, k/v bf16, skip into Bb) ----
    hipLaunchKernelGGL(k_lin2, dim3((n + 127) / 128, 4), dim3(256), 0, stream,
                       hhi, hlo, Bph, bq2, bk2, bv2, bs2, qb, kv16, Bb, n);
    hipLaunchKernelGGL((k_attn<0>), dim3(wb), dim3(256), 0, stream,
                       qb, (const unsigned int*)kv16,
                       rowptr, srcs, eas, uc + 2 * HC, uc + 3 * HC, Bb,
                       (unsigned short*)nullptr, (unsigned short*)nullptr, n);

    // ---- fc head ----
    hipLaunchKernelGGL(k_fc, dim3(wb), dim3(256), 0, stream, Bb, Wfc, bfc, (float*)d_out, n);
}

// Round 10
// 249.848 us; speedup vs baseline: 1.9489x; 1.0998x over previous
//
#include <hip/hip_runtime.h>

// TemporalGNN: 2x TransformerConv(H=2, C=64) + edge encoder + fc head.
// Edge encoder is rank-1 (edge_attr is [E,1]): eh_l = ea[e]*u_l + c_l.
// Edge phase: stable counting-sort by dst; one wave per dst node, split into
// two 32-lane halves each owning an edge stream (lane = 4 channels).
// Algebraic fold: q.(k+eh) = q.k + ea*(q.u) + (q.c); V-side eh deferred via
// sea = sum(pw*ea). R9 was VALU-issue bound at ~37 instrs/edge; this is ~20.
// Layer-2 linears: MFMA GEMM, split-bf16 A x bf16 B, 32 KB LDS B panel;
// grid (4, nb) so same-A quarter blocks are dispatch-adjacent (L2/L3 reuse).

#define HC 128   // H*C

typedef __attribute__((ext_vector_type(8))) short bf16x8;
typedef __attribute__((ext_vector_type(4))) float f32x4;

__device__ __forceinline__ unsigned bf16_rne(float f) {
    unsigned u = __float_as_uint(f);
    return (u + 0x7fffu + ((u >> 16) & 1u)) >> 16;
}

// ---------- rank-1 edge-encoder precompute ----------
__global__ void k_uc(const float* __restrict__ We_enc, const float* __restrict__ be_enc,
                     const float* __restrict__ We1, const float* __restrict__ We2,
                     float* __restrict__ uc) {
    int c = threadIdx.x;  // 0..127
    float u1 = 0.f, c1 = 0.f, u2 = 0.f, c2 = 0.f;
    for (int j = 0; j < 64; ++j) {
        float we = We_enc[j], be = be_enc[j];
        float w1 = We1[j * HC + c], w2 = We2[j * HC + c];
        u1 += we * w1; c1 += be * w1;
        u2 += we * w2; c2 += be * w2;
    }
    uc[c] = u1; uc[HC + c] = c1; uc[2 * HC + c] = u2; uc[3 * HC + c] = c2;
}

// ---------- pack layer-2 weights to bf16, B^T layout [n=512][k=128] ----------
__global__ __launch_bounds__(256) void k_wpack(
    const float* __restrict__ Wq, const float* __restrict__ Wk,
    const float* __restrict__ Wv, const float* __restrict__ Ws,
    unsigned short* __restrict__ Bph) {
    int t = blockIdx.x * 256 + threadIdx.x;   // 0..65535
    int nn = t >> 7;        // 0..511
    int kk = t & 127;
    int mat = nn >> 7, c = nn & 127;
    const float* W = (mat == 0) ? Wq : (mat == 1) ? Wk : (mat == 2) ? Wv : Ws;
    Bph[nn * 128 + kk] = (unsigned short)bf16_rne(W[kk * 128 + c]);
}

// ---------- CSR build (stable counting sort by dst) ----------
__global__ __launch_bounds__(256) void k_hist(const int* __restrict__ ei, int* __restrict__ deg, int E) {
    int t = blockIdx.x * blockDim.x + threadIdx.x;
    if (t < E) atomicAdd(&deg[ei[E + t]], 1);
}

// 3-pass hierarchical exclusive scan: deg[n] -> rowptr[n+1].
__global__ __launch_bounds__(256) void k_scan1(const int* __restrict__ deg, int* __restrict__ bsum, int n) {
    int t = blockIdx.x * 256 + threadIdx.x;
    int v = (t < n) ? deg[t] : 0;
#pragma unroll
    for (int off = 1; off < 64; off <<= 1) v += __shfl_xor(v, off);
    __shared__ int wsum[4];
    int lane = threadIdx.x & 63, w = threadIdx.x >> 6;
    if (lane == 0) wsum[w] = v;
    __syncthreads();
    if (threadIdx.x == 0) bsum[blockIdx.x] = wsum[0] + wsum[1] + wsum[2] + wsum[3];
}

__global__ __launch_bounds__(256) void k_scan2(int* __restrict__ bsum, int nb) {
    __shared__ int sh[256];
    int t = threadIdx.x;
    int v = (t < nb) ? bsum[t] : 0;
    sh[t] = v;
    __syncthreads();
    for (int off = 1; off < 256; off <<= 1) {
        int x = (t >= off) ? sh[t - off] : 0;
        __syncthreads();
        sh[t] += x;
        __syncthreads();
    }
    if (t < nb) bsum[t] = sh[t] - v;   // exclusive
}

__global__ __launch_bounds__(256) void k_scan3(const int* __restrict__ deg, const int* __restrict__ bsum,
                                               int* __restrict__ rowptr, int n, int E) {
    int t = blockIdx.x * 256 + threadIdx.x;
    int tid = threadIdx.x;
    int v = (t < n) ? deg[t] : 0;
    __shared__ int sh[256];
    sh[tid] = v;
    __syncthreads();
    for (int off = 1; off < 256; off <<= 1) {
        int x = (tid >= off) ? sh[tid - off] : 0;
        __syncthreads();
        sh[tid] += x;
        __syncthreads();
    }
    if (t < n) rowptr[t] = bsum[blockIdx.x] + sh[tid] - v;
    if (t == 0) rowptr[n] = E;
}

__global__ __launch_bounds__(256) void k_scatter(const int* __restrict__ ei, const int* __restrict__ rowptr,
                                                 int* __restrict__ cursor, int* __restrict__ eid, int E) {
    int t = blockIdx.x * blockDim.x + threadIdx.x;
    if (t >= E) return;
    int dst = ei[E + t];
    int pos = rowptr[dst] + atomicAdd(&cursor[dst], 1);
    eid[pos] = t;
}

__global__ __launch_bounds__(256) void k_bsort(const int* __restrict__ rowptr, int* __restrict__ eid, int n) {
    int t = blockIdx.x * blockDim.x + threadIdx.x;
    if (t >= n) return;
    int b = rowptr[t], e = rowptr[t + 1];
    for (int i = b + 1; i < e; ++i) {
        int key = eid[i];
        int j = i - 1;
        while (j >= b && eid[j] > key) { eid[j + 1] = eid[j]; --j; }
        eid[j + 1] = key;
    }
}

__global__ __launch_bounds__(256) void k_gather(const int* __restrict__ eid, const int* __restrict__ ei,
                                                const float* __restrict__ ea,
                                                int* __restrict__ srcs, float* __restrict__ eas, int E) {
    int t = blockIdx.x * blockDim.x + threadIdx.x;
    if (t >= E) return;
    int id = eid[t];
    srcs[t] = ei[id];
    eas[t] = ea[id];
}

// ---------- layer-1 node linears (K=6, vector ALU) ----------
// q,o stored f32; k,v stored packed bf16 into interleaved kv rows [256 ushort].
__global__ __launch_bounds__(256) void k_lin6(
    const float* __restrict__ X, int n,
    const float* __restrict__ Wq, const float* __restrict__ bq,
    const float* __restrict__ Wk, const float* __restrict__ bk,
    const float* __restrict__ Wv, const float* __restrict__ bv,
    const float* __restrict__ Ws, const float* __restrict__ bs,
    float* __restrict__ q, unsigned short* __restrict__ kv,
    float* __restrict__ o) {
    __shared__ float xs[16][6];
    const int base = blockIdx.x * 16;
    const int tid = threadIdx.x;
    for (int i = tid; i < 16 * 6; i += 256) {
        int ni = base + i / 6;
        xs[i / 6][i % 6] = (ni < n) ? X[(size_t)ni * 6 + (i % 6)] : 0.f;
    }
    __syncthreads();
    const int c = tid & 127;
    const int m = tid >> 7;  // 0 -> (q,k), 1 -> (v,o)
    const float* WA = m ? Wv : Wq;
    const float* WB = m ? Ws : Wk;
    float accA[16], accB[16];
#pragma unroll
    for (int i = 0; i < 16; ++i) { accA[i] = 0.f; accB[i] = 0.f; }
    for (int j = 0; j < 6; ++j) {
        float w0 = WA[j * HC + c];
        float w1 = WB[j * HC + c];
#pragma unroll
        for (int i = 0; i < 16; ++i) {
            float xv = xs[i][j];
            accA[i] += xv * w0;
            accB[i] += xv * w1;
        }
    }
    if (m == 0) {
        const float bA = bq[c], bB = bk[c];
#pragma unroll
        for (int i = 0; i < 16; ++i) {
            int ni = base + i;
            if (ni < n) {
                q[(size_t)ni * HC + c] = accA[i] + bA;
                kv[(size_t)ni * 256 + c] = (unsigned short)bf16_rne(accB[i] + bB);
            }
        }
    } else {
        const float bA = bv[c], bB = bs[c];
#pragma unroll
        for (int i = 0; i < 16; ++i) {
            int ni = base + i;
            if (ni < n) {
                kv[(size_t)ni * 256 + 128 + c] = (unsigned short)bf16_rne(accA[i] + bA);
                o[(size_t)ni * HC + c] = accB[i] + bB;
            }
        }
    }
}

// ---------- layer-2 node linears: split-A bf16 MFMA GEMM, LDS-staged bf16 B ----------
// Grid (4, ceil(n/128)). blockIdx.x = col quarter = matrix {q,k,v,s} --
// x-fastest dispatch makes the 4 quarters sharing an A panel adjacent.
__global__ __launch_bounds__(256, 4) void k_lin2(
    const unsigned short* __restrict__ hhi, const unsigned short* __restrict__ hlo,
    const unsigned short* __restrict__ Bph,
    const float* __restrict__ bq, const float* __restrict__ bk,
    const float* __restrict__ bv, const float* __restrict__ bs,
    float* __restrict__ q, unsigned short* __restrict__ kv,
    float* __restrict__ o, int n) {
    __shared__ unsigned short Bs[128][128];   // 32 KB
    const int tid = threadIdx.x;
    const int cq = blockIdx.x;                // matrix index
    for (int i = tid; i < 128 * 16; i += 256) {
        int kk8 = i & 15;
        int nnl = i >> 4;
        bf16x8 val = *(const bf16x8*)&Bph[((size_t)(cq * 128 + nnl)) * 128 + kk8 * 8];
        int swk = (kk8 ^ (nnl & 7)) * 8;
        *(bf16x8*)&Bs[nnl][swk] = val;
    }
    __syncthreads();

    const int wid = tid >> 6, l = tid & 63;
    const int la = l & 15, lk = l >> 4;
    const int mb = blockIdx.y * 128;
    int nodeA0 = mb + wid * 32 + la;
    int nodeA1 = nodeA0 + 16;
    if (nodeA0 >= n) nodeA0 = n - 1;
    if (nodeA1 >= n) nodeA1 = n - 1;
    const int sw = (la & 7) << 3;
    f32x4 acc0[8], acc1[8];
#pragma unroll
    for (int nt = 0; nt < 8; ++nt) {
        acc0[nt] = (f32x4){0.f, 0.f, 0.f, 0.f};
        acc1[nt] = (f32x4){0.f, 0.f, 0.f, 0.f};
    }
    // double-buffered A fragments (static indices via full unroll)
    bf16x8 a0h[2], a0l[2], a1h[2], a1l[2];
    {
        const int ko = lk * 8;
        a0h[0] = *(const bf16x8*)&hhi[(size_t)nodeA0 * 128 + ko];
        a0l[0] = *(const bf16x8*)&hlo[(size_t)nodeA0 * 128 + ko];
        a1h[0] = *(const bf16x8*)&hhi[(size_t)nodeA1 * 128 + ko];
        a1l[0] = *(const bf16x8*)&hlo[(size_t)nodeA1 * 128 + ko];
    }
#pragma unroll
    for (int ks = 0; ks < 4; ++ks) {
        const int cur = ks & 1, nxt = cur ^ 1;
        if (ks < 3) {
            const int ko = lk * 8 + (ks + 1) * 32;
            a0h[nxt] = *(const bf16x8*)&hhi[(size_t)nodeA0 * 128 + ko];
            a0l[nxt] = *(const bf16x8*)&hlo[(size_t)nodeA0 * 128 + ko];
            a1h[nxt] = *(const bf16x8*)&hhi[(size_t)nodeA1 * 128 + ko];
            a1l[nxt] = *(const bf16x8*)&hlo[(size_t)nodeA1 * 128 + ko];
        }
        const int rk = (lk * 8 + ks * 32) ^ sw;
#pragma unroll
        for (int nt = 0; nt < 8; ++nt) {
            bf16x8 Bh = *(const bf16x8*)&Bs[nt * 16 + la][rk];
            acc0[nt] = __builtin_amdgcn_mfma_f32_16x16x32_bf16(a0h[cur], Bh, acc0[nt], 0, 0, 0);
            acc0[nt] = __builtin_amdgcn_mfma_f32_16x16x32_bf16(a0l[cur], Bh, acc0[nt], 0, 0, 0);
            acc1[nt] = __builtin_amdgcn_mfma_f32_16x16x32_bf16(a1h[cur], Bh, acc1[nt], 0, 0, 0);
            acc1[nt] = __builtin_amdgcn_mfma_f32_16x16x32_bf16(a1l[cur], Bh, acc1[nt], 0, 0, 0);
        }
    }
    const float* bias = (cq == 0) ? bq : (cq == 1) ? bk : (cq == 2) ? bv : bs;
    const int crow0 = mb + wid * 32 + lk * 4;
#pragma unroll
    for (int nt = 0; nt < 8; ++nt) {
        const int col = nt * 16 + la;
        const float bb = bias[col];
        if (cq == 0 || cq == 3) {
            float* out = (cq == 0) ? q : o;
#pragma unroll
            for (int j = 0; j < 4; ++j) {
                int n0 = crow0 + j;
                if (n0 < n) out[(size_t)n0 * 128 + col] = acc0[nt][j] + bb;
                int n1 = n0 + 16;
                if (n1 < n) out[(size_t)n1 * 128 + col] = acc1[nt][j] + bb;
            }
        } else {
            const int co = (cq == 1) ? col : 128 + col;
#pragma unroll
            for (int j = 0; j < 4; ++j) {
                int n0 = crow0 + j;
                if (n0 < n) kv[(size_t)n0 * 256 + co] = (unsigned short)bf16_rne(acc0[nt][j] + bb);
                int n1 = n0 + 16;
                if (n1 < n) kv[(size_t)n1 * 256 + co] = (unsigned short)bf16_rne(acc1[nt][j] + bb);
            }
        }
    }
}

// ---------- fused online-softmax attention, one wave per dst node ----------
// Wave = two 32-lane halves, each owning one edge stream (even/odd edges).
// Within a half: lanes 0-15 = head0, 16-31 = head1; lane holds 4 channels.
// Edge-encoder folded out: a = (q.k + ea*qu + qc)/8; V-side via sea.
template <int MODE>
__global__ __launch_bounds__(256) void k_attn(
    const float* __restrict__ q, const unsigned short* __restrict__ kvp,
    const int* __restrict__ rowptr, const int* __restrict__ srcs, const float* __restrict__ eas,
    const float* __restrict__ ucu, const float* __restrict__ ucc,
    float* __restrict__ io, unsigned short* __restrict__ hhi, unsigned short* __restrict__ hlo,
    int n) {
    int wid = (int)((blockIdx.x * (size_t)blockDim.x + threadIdx.x) >> 6);
    int lane = threadIdx.x & 63;
    if (wid >= n) return;
    const int half = lane >> 5;       // edge stream (0=even edges, 1=odd)
    const int hl = lane & 31;
    const int ch = hl * 4;            // 4 channels; hl 0-15 head0, 16-31 head1

    float4 qr = *(const float4*)&q[(size_t)wid * 128 + ch];
    float4 uu = *(const float4*)&ucu[ch];
    float4 cc = *(const float4*)&ucc[ch];

    // per-head scalars qu = q.u, qc = q.c (reduced over the 16-lane head group)
    float qu = qr.x * uu.x + qr.y * uu.y + qr.z * uu.z + qr.w * uu.w;
    float qc = qr.x * cc.x + qr.y * cc.y + qr.z * cc.z + qr.w * cc.w;
#pragma unroll
    for (int off = 1; off < 16; off <<= 1) {
        qu += __shfl_xor(qu, off);
        qc += __shfl_xor(qc, off);
    }

    int b = rowptr[wid], e = rowptr[wid + 1];
    float m = -3.0e38f, s = 0.f, sea = 0.f;
    float av0 = 0.f, av1 = 0.f, av2 = 0.f, av3 = 0.f;

    if (b < e) {
        int pi = b + half;
        bool val = pi < e;
        int pc = val ? pi : e - 1;
        int src = srcs[pc];
        float eav = eas[pc];
        const unsigned short* row = &kvp[(size_t)src * 256 + ch];
        uint2 ku = *(const uint2*)row;
        uint2 vu = *(const uint2*)(row + 128);
        for (int p = b; p < e; p += 2) {
            // prefetch next pair
            int pn = p + 2 + half;
            bool valn = pn < e;
            int pcn = valn ? pn : e - 1;
            int srcn = srcs[pcn];
            float eavn = eas[pcn];
            const unsigned short* rown = &kvp[(size_t)srcn * 256 + ch];
            uint2 kun = *(const uint2*)rown;
            uint2 vun = *(const uint2*)(rown + 128);

            float k0 = __uint_as_float(ku.x << 16);
            float k1 = __uint_as_float(ku.x & 0xffff0000u);
            float k2 = __uint_as_float(ku.y << 16);
            float k3 = __uint_as_float(ku.y & 0xffff0000u);
            float d = qr.x * k0 + qr.y * k1 + qr.z * k2 + qr.w * k3;
#pragma unroll
            for (int off = 1; off < 16; off <<= 1) d += __shfl_xor(d, off);
            float a = val ? (d + fmaf(eav, qu, qc)) * 0.125f : -INFINITY;
            float nm = fmaxf(m, a);
            float sc = __expf(m - nm);
            float pw = __expf(a - nm);
            float v0 = __uint_as_float(vu.x << 16);
            float v1 = __uint_as_float(vu.x & 0xffff0000u);
            float v2 = __uint_as_float(vu.y << 16);
            float v3 = __uint_as_float(vu.y & 0xffff0000u);
            s = fmaf(s, sc, pw);
            sea = fmaf(sea, sc, pw * eav);
            av0 = fmaf(av0, sc, pw * v0);
            av1 = fmaf(av1, sc, pw * v1);
            av2 = fmaf(av2, sc, pw * v2);
            av3 = fmaf(av3, sc, pw * v3);
            m = nm;
            ku = kun; vu = vun; eav = eavn; val = valn;
        }
    }

    // merge the two edge streams (safe when one/both empty: m stays -3e38)
    {
        float om = __shfl_xor(m, 32);
        float os = __shfl_xor(s, 32);
        float osea = __shfl_xor(sea, 32);
        float o0 = __shfl_xor(av0, 32);
        float o1 = __shfl_xor(av1, 32);
        float o2 = __shfl_xor(av2, 32);
        float o3 = __shfl_xor(av3, 32);
        float nm = fmaxf(m, om);
        float scS = __expf(m - nm);
        float scO = __expf(om - nm);
        s = s * scS + os * scO;
        sea = sea * scS + osea * scO;
        av0 = av0 * scS + o0 * scO;
        av1 = av1 * scS + o1 * scO;
        av2 = av2 * scS + o2 * scO;
        av3 = av3 * scS + o3 * scO;
    }

    if (half == 0) {
        float inv = 1.f / (s + 1e-16f);
        float4 skip = *(const float4*)&io[(size_t)wid * 128 + ch];
        float r0 = (av0 + uu.x * sea + cc.x * s) * inv + skip.x;
        float r1 = (av1 + uu.y * sea + cc.y * s) * inv + skip.y;
        float r2 = (av2 + uu.z * sea + cc.z * s) * inv + skip.z;
        float r3 = (av3 + uu.w * sea + cc.w * s) * inv + skip.w;
        if (MODE == 1) {
            r0 = fmaxf(r0, 0.f); r1 = fmaxf(r1, 0.f);
            r2 = fmaxf(r2, 0.f); r3 = fmaxf(r3, 0.f);
            unsigned h0 = bf16_rne(r0), h1 = bf16_rne(r1);
            unsigned h2 = bf16_rne(r2), h3 = bf16_rne(r3);
            unsigned l0 = bf16_rne(r0 - __uint_as_float(h0 << 16));
            unsigned l1 = bf16_rne(r1 - __uint_as_float(h1 << 16));
            unsigned l2 = bf16_rne(r2 - __uint_as_float(h2 << 16));
            unsigned l3 = bf16_rne(r3 - __uint_as_float(h3 << 16));
            ushort4 hv = make_ushort4((unsigned short)h0, (unsigned short)h1,
                                      (unsigned short)h2, (unsigned short)h3);
            ushort4 lv = make_ushort4((unsigned short)l0, (unsigned short)l1,
                                      (unsigned short)l2, (unsigned short)l3);
            *(ushort4*)&hhi[(size_t)wid * 128 + ch] = hv;
            *(ushort4*)&hlo[(size_t)wid * 128 + ch] = lv;
        } else {
            *(float4*)&io[(size_t)wid * 128 + ch] = make_float4(r0, r1, r2, r3);
        }
    }
}

// ---------- fc head (relu fused), one wave per node ----------
__global__ __launch_bounds__(256) void k_fc(
    const float* __restrict__ h, const float* __restrict__ Wfc,
    const float* __restrict__ bfc, float* __restrict__ out, int n) {
    int w = (int)((blockIdx.x * (size_t)blockDim.x + threadIdx.x) >> 6);
    int lane = threadIdx.x & 63;
    if (w >= n) return;
    const float2* h2 = (const float2*)h;
    const float2* w2 = (const float2*)Wfc;
    float2 hv = h2[(size_t)w * 64 + lane];
    float2 wv = w2[lane];
    float vsum = fmaxf(hv.x, 0.f) * wv.x + fmaxf(hv.y, 0.f) * wv.y;
#pragma unroll
    for (int off = 1; off < 64; off <<= 1) vsum += __shfl_xor(vsum, off);
    if (lane == 0) out[w] = vsum + bfc[0];
}

extern "C" void kernel_launch(void* const* d_in, const int* in_sizes, int n_in,
                              void* d_out, int out_size, void* d_ws, size_t ws_size,
                              hipStream_t stream) {
    const float* x      = (const float*)d_in[0];
    const int*   ei     = (const int*)d_in[1];
    const float* ea     = (const float*)d_in[2];
    const float* We_enc = (const float*)d_in[3];
    const float* be_enc = (const float*)d_in[4];
    const float* Wq1 = (const float*)d_in[5],  *bq1 = (const float*)d_in[6];
    const float* Wk1 = (const float*)d_in[7],  *bk1 = (const float*)d_in[8];
    const float* Wv1 = (const float*)d_in[9],  *bv1 = (const float*)d_in[10];
    const float* We1 = (const float*)d_in[11];
    const float* Ws1 = (const float*)d_in[12], *bs1 = (const float*)d_in[13];
    const float* Wq2 = (const float*)d_in[14], *bq2 = (const float*)d_in[15];
    const float* Wk2 = (const float*)d_in[16], *bk2 = (const float*)d_in[17];
    const float* Wv2 = (const float*)d_in[18], *bv2 = (const float*)d_in[19];
    const float* We2 = (const float*)d_in[20];
    const float* Ws2 = (const float*)d_in[21], *bs2 = (const float*)d_in[22];
    const float* Wfc = (const float*)d_in[23], *bfc = (const float*)d_in[24];

    const int n = in_sizes[0] / 6;   // 50000
    const int E = in_sizes[2];       // 409600

    float* ws = (float*)d_ws;
    size_t off = 0;
    float* qb = ws + off; off += (size_t)n * HC;
    float* Bb = ws + off; off += (size_t)n * HC;   // skip-init / h buffer
    unsigned short* kv16 = (unsigned short*)(ws + off); off += (size_t)n * HC;  // interleaved k|v bf16
    int* rowptr = (int*)(ws + off); off += (size_t)(n + 1);
    int* deg    = (int*)(ws + off); off += (size_t)n;   // also scatter cursor
    int* bsum   = (int*)(ws + off); off += 256;
    int* eid    = (int*)(ws + off); off += (size_t)E;
    int* srcs   = (int*)(ws + off); off += (size_t)E;
    float* eas  = ws + off; off += (size_t)E;
    float* uc   = ws + off; off += 512;
    unsigned short* hhi = (unsigned short*)(ws + off); off += (size_t)n * HC / 2;
    unsigned short* hlo = (unsigned short*)(ws + off); off += (size_t)n * HC / 2;
    unsigned short* Bph = (unsigned short*)(ws + off); off += 512 * 128 / 2;

    const int eb = (E + 255) / 256;
    const int nb = (n + 255) / 256;
    const int wb = (int)(((size_t)n * 64 + 255) / 256);

    hipLaunchKernelGGL(k_uc, dim3(1), dim3(128), 0, stream, We_enc, be_enc, We1, We2, uc);
    hipLaunchKernelGGL(k_wpack, dim3(256), dim3(256), 0, stream, Wq2, Wk2, Wv2, Ws2, Bph);

    // ---- CSR build (shared by both layers) ----
    hipMemsetAsync(deg, 0, (size_t)n * sizeof(int), stream);
    hipLaunchKernelGGL(k_hist, dim3(eb), dim3(256), 0, stream, ei, deg, E);
    hipLaunchKernelGGL(k_scan1, dim3(nb), dim3(256), 0, stream, deg, bsum, n);
    hipLaunchKernelGGL(k_scan2, dim3(1), dim3(256), 0, stream, bsum, nb);
    hipLaunchKernelGGL(k_scan3, dim3(nb), dim3(256), 0, stream, deg, bsum, rowptr, n, E);
    hipMemsetAsync(deg, 0, (size_t)n * sizeof(int), stream);  // reuse as cursor
    hipLaunchKernelGGL(k_scatter, dim3(eb), dim3(256), 0, stream, ei, rowptr, deg, eid, E);
    hipLaunchKernelGGL(k_bsort, dim3(nb), dim3(256), 0, stream, rowptr, eid, n);
    hipLaunchKernelGGL(k_gather, dim3(eb), dim3(256), 0, stream, eid, ei, ea, srcs, eas, E);

    // ---- layer 1 ----
    hipLaunchKernelGGL(k_lin6, dim3((n + 15) / 16), dim3(256), 0, stream,
                       x, n, Wq1, bq1, Wk1, bk1, Wv1, bv1, Ws1, bs1, qb, kv16, Bb);
    hipLaunchKernelGGL((k_attn<1>), dim3(wb), dim3(256), 0, stream,
                       qb, kv16, rowptr, srcs, eas, uc, uc + HC, Bb, hhi, hlo, n);

    // ---- layer 2 (MFMA GEMM reads hhi/hlo; writes q f32, k/v bf16, skip into Bb) ----
    hipLaunchKernelGGL(k_lin2, dim3(4, (n + 127) / 128), dim3(256), 0, stream,
                       hhi, hlo, Bph, bq2, bk2, bv2, bs2, qb, kv16, Bb, n);
    hipLaunchKernelGGL((k_attn<0>), dim3(wb), dim3(256), 0, stream,
                       qb, kv16, rowptr, srcs, eas, uc + 2 * HC, uc + 3 * HC, Bb,
                       (unsigned short*)nullptr, (unsigned short*)nullptr, n);

    // ---- fc head ----
    hipLaunchKernelGGL(k_fc, dim3(wb), dim3(256), 0, stream, Bb, Wfc, bfc, (float*)d_out, n);
}